// Round 6
// baseline (285.465 us; speedup 1.0000x reference)
//
#include <hip/hip_runtime.h>
#include <math.h>

#define BB   2
#define NN   8192
#define SS   1024
#define KK   32
#define HID  256
#define NTH  256
#define PPT  32        // candidates per thread (NN/NTH)
#define SENT 0xFFFFFFFFFFFFFFFFULL

typedef unsigned long long u64;
typedef unsigned int       u32;
typedef float v2f __attribute__((ext_vector_type(2)));

// float4 component by constant index (folds under full unroll)
#define F4C(v, i) ((i)==0?(v).x:((i)==1?(v).y:((i)==2?(v).z:(v).w)))

// sorted-8 insertion: compare-swap carry chain (keeps s0..s7 ascending, drops max)
#define CSW(SI) { const u64 mn = x < (SI) ? x : (SI); const u64 mx = x < (SI) ? (SI) : x; (SI) = mn; x = mx; }
#define INS(KV) { u64 x = (KV); CSW(s0) CSW(s1) CSW(s2) CSW(s3) CSW(s4) CSW(s5) CSW(s6) CSW(s7) }

// tanh via hardware exp/rcp: tanh(y) = 1 - 2/(1+e^{2y}); saturates correctly.
__device__ __forceinline__ float tanh_fast(float y) {
    const float e = __expf(2.0f * y);
    const float r = __builtin_amdgcn_rcpf(e + 1.0f);
    return fmaf(-2.0f, r, 1.0f);
}

__global__ __launch_bounds__(NTH, 4)
void snp_kernel(const float* __restrict__ pos,     // (B,N,3)
                const int*   __restrict__ snidx,   // (S,)
                const float* __restrict__ w_in,    // (3,HID)
                const float* __restrict__ b_in,    // (HID,)
                const float* __restrict__ w1,      // (HID,HID)
                const float* __restrict__ b1,      // (HID,)
                const float* __restrict__ w2,      // (HID,HID)
                const float* __restrict__ b2,      // (HID,)
                float*       __restrict__ out)     // (B,S,HID)
{
    const int bs   = blockIdx.x;        // 0 .. B*S-1
    const int b    = bs / SS;
    const int s    = bs - b * SS;
    const int t    = threadIdx.x;
    const int lane = t & 63;
    const int wv   = t >> 6;

    // 32 KB LDS. KNN scratch inside h0 rows 28-31 (dead before phase 4 writes).
    __shared__ __align__(16) float h0[KK][HID];
    u64*   wl  = (u64*)&h0[28][0];      // 4 waves x 32 sorted keys (1 KB, rows 28-29)
    int*   nbr = (int*)&h0[30][0];      // 32 int
    float* nbc = &h0[31][0];            // 96 f32

    const float* posb = pos + (size_t)b * (NN * 3);
    const int   sp = snidx[s];
    const float sx = posb[sp*3 + 0];
    const float sy = posb[sp*3 + 1];
    const float sz = posb[sp*3 + 2];

    // ---- Phase 1: stream distances (reference rounding), per-lane sorted top-8 ----
    u64 s0=SENT,s1=SENT,s2=SENT,s3=SENT,s4=SENT,s5=SENT,s6=SENT,s7=SENT;
#pragma unroll 4
    for (int c = 0; c < PPT; ++c) {
        const int i = c * NTH + t;                 // coalesced across lanes
        const float dx = __fsub_rn(sx, posb[i*3 + 0]);
        const float dy = __fsub_rn(sy, posb[i*3 + 1]);
        const float dz = __fsub_rn(sz, posb[i*3 + 2]);
        const float sq = __fadd_rn(__fadd_rn(__fmul_rn(dx,dx), __fmul_rn(dy,dy)),
                                   __fmul_rn(dz,dz));
        const u64 kv = ((u64)__float_as_uint(__fsqrt_rn(sq)) << 32) | (u32)i;
        INS(kv);
    }
    int nv = 8;

    // ---- Phase 2: wave-local 32 min-extractions, NO barriers ----
#pragma unroll 1
    for (int it = 0; it < KK; ++it) {
        u64 m = s0;                                 // offer own current min
#pragma unroll
        for (int off = 32; off > 0; off >>= 1) {
            const u64 o = __shfl_xor(m, off, 64);
            m = o < m ? o : m;
        }
        if (lane == 0) wl[wv*KK + it] = m;          // ascending per wave
        if (s0 == m) {                              // unique owner (idx in key)
            s0=s1; s1=s2; s2=s3; s3=s4; s4=s5; s5=s6; s6=s7; s7=SENT;
            if (--nv == 0) {                        // cold: lane owned 8 of wave top-32
                const u64 last = m;
                s0=s1=s2=s3=s4=s5=s6=s7=SENT;
#pragma unroll 4
                for (int c = 0; c < PPT; ++c) {
                    const int i = c * NTH + t;
                    const float dx = __fsub_rn(sx, posb[i*3 + 0]);
                    const float dy = __fsub_rn(sy, posb[i*3 + 1]);
                    const float dz = __fsub_rn(sz, posb[i*3 + 2]);
                    const float sq = __fadd_rn(__fadd_rn(__fmul_rn(dx,dx), __fmul_rn(dy,dy)),
                                               __fmul_rn(dz,dz));
                    u64 kv = ((u64)__float_as_uint(__fsqrt_rn(sq)) << 32) | (u32)i;
                    kv = kv > last ? kv : SENT;     // only keys after lastPopped
                    INS(kv);
                }
                nv = (int)(s0!=SENT)+(int)(s1!=SENT)+(int)(s2!=SENT)+(int)(s3!=SENT)
                   + (int)(s4!=SENT)+(int)(s5!=SENT)+(int)(s6!=SENT)+(int)(s7!=SENT);
            }
        }
    }
    __syncthreads();

    // ---- Phase 2b: wave 0 merges 4 sorted lists via bitonic merges ----
    if (t < 64) {
        auto bmerge = [&](u64 x) -> u64 {          // full-asc sort of bitonic seq
#pragma unroll
            for (int off = 32; off > 0; off >>= 1) {
                const u64 p  = __shfl_xor(x, off, 64);
                const u64 mn = x < p ? x : p;
                const u64 mx = x < p ? p : x;
                x = (lane & off) ? mx : mn;
            }
            return x;
        };
        u64 a = (lane < 32) ? wl[lane] : wl[32 + (63 - lane)];       // L0 asc + L1 desc
        a = bmerge(a);                                               // lanes0-31: top32(L0∪L1)
        u64 b2v = (lane < 32) ? wl[64 + lane] : wl[96 + (63 - lane)];// L2 asc + L3 desc
        b2v = bmerge(b2v);                                           // lanes0-31: top32(L2∪L3)
        const u64 sw = __shfl(b2v, 63 - lane, 64);                   // reverse M23
        u64 cf = (lane < 32) ? a : sw;
        cf = bmerge(cf);                                             // global top-32 asc
        if (lane < 32) nbr[lane] = (int)(u32)cf;                     // idx in low bits
    }
    __syncthreads();

    // ---- Phase 3: gather neighbor coords ----
    if (t < KK * 3) {
        nbc[t] = posb[(size_t)nbr[t / 3] * 3 + (t % 3)];
    }
    __syncthreads();

    // ---- Phase 4: h0 = coords @ w_in + b_in + sincos PE (thread = channel) ----
    {
        const int  c     = t;
        const int  dimi  = c / 84;                  // 84 = 2*42 channels per dim
        const int  cc    = c - dimi * 84;
        const bool hasPe = c < 252;
        const bool isCos = cc >= 42;
        const int  f     = isCos ? cc - 42 : cc;
        const float fcoef = (float)(-9.210340371976184 / 41.0);
        const float freqv = expf((float)f * fcoef);
        const int  di    = hasPe ? dimi : 0;

        const float wi0 = w_in[0*HID + c];
        const float wi1 = w_in[1*HID + c];
        const float wi2 = w_in[2*HID + c];
        const float bi  = b_in[c];

        auto h0val = [&](float x0, float x1, float x2) -> float {
            float v = fmaf(x2, wi2, fmaf(x1, wi1, fmaf(x0, wi0, bi)));
            if (hasPe) {
                const float xv  = (di == 0) ? x0 : ((di == 1) ? x1 : x2);
                const float ang = xv * freqv;
                v += isCos ? __cosf(ang) : __sinf(ang);   // native (args |x|<~6)
            }
            return v;
        };

        // rows 0..30: row 31 (nbc) untouched; rows 28-30 scratch is dead now
#pragma unroll 4
        for (int k = 0; k < KK - 1; ++k) {
            const float x0 = nbc[3*k+0], x1 = nbc[3*k+1], x2 = nbc[3*k+2];
            h0[k][c] = h0val(x0, x1, x2);
        }
        // k=31: its coords live where row 31 will be written -> stage via regs
        __syncthreads();
        const float x0 = nbc[93], x1 = nbc[94], x2 = nbc[95];
        __syncthreads();
        h0[KK-1][c] = h0val(x0, x1, x2);
    }
    __syncthreads();

    // ---- MLP: register-tiled, 8 channels x 4 k-rows per thread ----
    // Halves DS-pipe reads vs 4ch x 8k (4 uniform b128/j-step instead of 8).
    // Threads t and t+32 share ct -> duplicate w addresses coalesce in cache.
    const int ct = t & 31;           // c-tile (8 channels)
    const int kt = t >> 5;           // k-group (4 rows)
    const int cb = ct * 8;
    const int kb = kt * 4;

    // acc pairs along ci: a[p][kk] covers channels {2p,2p+1} of this ct, k row kb+kk
    v2f a_[4][4];

    // ---- Phase 5: layer 1 (h0 @ w1 + b1) ----
    {
        const float4 bv0 = *(const float4*)&b1[cb];
        const float4 bv1 = *(const float4*)&b1[cb + 4];
        const v2f bp[4] = {{bv0.x,bv0.y},{bv0.z,bv0.w},{bv1.x,bv1.y},{bv1.z,bv1.w}};
#pragma unroll
        for (int p = 0; p < 4; ++p)
#pragma unroll
            for (int kk = 0; kk < 4; ++kk) a_[p][kk] = bp[p];

        for (int j = 0; j < HID; j += 4) {
            float4 h[4];
#pragma unroll
            for (int kk = 0; kk < 4; ++kk)
                h[kk] = *(const float4*)&h0[kb + kk][j];    // uniform b128 (2 addrs/wave)
            float4 w[4][2];
#pragma unroll
            for (int jj = 0; jj < 4; ++jj) {
                w[jj][0] = *(const float4*)&w1[(j + jj)*HID + cb];
                w[jj][1] = *(const float4*)&w1[(j + jj)*HID + cb + 4];
            }
#pragma unroll
            for (int jj = 0; jj < 4; ++jj) {
#pragma unroll
                for (int p = 0; p < 4; ++p) {
                    const v2f wp = {F4C(w[jj][p>>1], (p&1)*2),
                                    F4C(w[jj][p>>1], (p&1)*2+1)};
#pragma unroll
                    for (int kk = 0; kk < 4; ++kk) {
                        const float hv = F4C(h[kk], jj);
                        const v2f hs = {hv, hv};              // op_sel-foldable splat
                        a_[p][kk] = __builtin_elementwise_fma(hs, wp, a_[p][kk]);
                    }
                }
            }
        }
    }
    __syncthreads();                                 // all h0 reads done

    // gelu (tanh approx), write back into h0
    {
        const float kA = 0.7978845608028654f;        // sqrt(2/pi)
#pragma unroll
        for (int kk = 0; kk < 4; ++kk) {
            float4 g0, g1;
#pragma unroll
            for (int ci = 0; ci < 8; ++ci) {
                const float x  = (ci & 1) ? a_[ci>>1][kk].y : a_[ci>>1][kk].x;
                const float x3 = x * x * x;
                const float tv = tanh_fast(kA * fmaf(0.044715f, x3, x));
                const float gv = 0.5f * x * (1.0f + tv);
                if      (ci == 0) g0.x = gv; else if (ci == 1) g0.y = gv;
                else if (ci == 2) g0.z = gv; else if (ci == 3) g0.w = gv;
                else if (ci == 4) g1.x = gv; else if (ci == 5) g1.y = gv;
                else if (ci == 6) g1.z = gv; else               g1.w = gv;
            }
            *(float4*)&h0[kb + kk][cb]     = g0;
            *(float4*)&h0[kb + kk][cb + 4] = g1;
        }
    }
    __syncthreads();

    // ---- Phase 6: layer 2 (@ w2), partial over this thread's 4 k-rows ----
    {
        const v2f z = {0.0f, 0.0f};
#pragma unroll
        for (int p = 0; p < 4; ++p)
#pragma unroll
            for (int kk = 0; kk < 4; ++kk) a_[p][kk] = z;

        for (int j = 0; j < HID; j += 4) {
            float4 h[4];
#pragma unroll
            for (int kk = 0; kk < 4; ++kk)
                h[kk] = *(const float4*)&h0[kb + kk][j];
            float4 w[4][2];
#pragma unroll
            for (int jj = 0; jj < 4; ++jj) {
                w[jj][0] = *(const float4*)&w2[(j + jj)*HID + cb];
                w[jj][1] = *(const float4*)&w2[(j + jj)*HID + cb + 4];
            }
#pragma unroll
            for (int jj = 0; jj < 4; ++jj) {
#pragma unroll
                for (int p = 0; p < 4; ++p) {
                    const v2f wp = {F4C(w[jj][p>>1], (p&1)*2),
                                    F4C(w[jj][p>>1], (p&1)*2+1)};
#pragma unroll
                    for (int kk = 0; kk < 4; ++kk) {
                        const float hv = F4C(h[kk], jj);
                        const v2f hs = {hv, hv};
                        a_[p][kk] = __builtin_elementwise_fma(hs, wp, a_[p][kk]);
                    }
                }
            }
        }
    }
    __syncthreads();                                 // h0 reads done; reuse as scratch

    // per-thread partial sums over its 4 k's (k ascending): 8 channels
    // scratch layout: part[kt][ct][ch8] flat floats = kt*256 + ct*8 + ch
    {
        float4 p0, p1;
#pragma unroll
        for (int ci = 0; ci < 8; ++ci) {
            float p = (ci & 1) ? a_[ci>>1][0].y : a_[ci>>1][0].x;
#pragma unroll
            for (int kk = 1; kk < 4; ++kk)
                p += (ci & 1) ? a_[ci>>1][kk].y : a_[ci>>1][kk].x;
            if      (ci == 0) p0.x = p; else if (ci == 1) p0.y = p;
            else if (ci == 2) p0.z = p; else if (ci == 3) p0.w = p;
            else if (ci == 4) p1.x = p; else if (ci == 5) p1.y = p;
            else if (ci == 6) p1.z = p; else               p1.w = p;
        }
        float* sc = &h0[0][0];
        *(float4*)&sc[kt*256 + ct*8]     = p0;
        *(float4*)&sc[kt*256 + ct*8 + 4] = p1;
    }
    __syncthreads();

    // cross-kt reduce (kt ascending) + bias + mean; thread t = channel t
    {
        const float* sc = &h0[0][0];
        float tot = sc[t];
#pragma unroll
        for (int g = 1; g < 8; ++g) tot += sc[g*256 + t];
        out[(size_t)bs * HID + t] = fmaf(tot, 1.0f / KK, b2[t]);
    }
}

extern "C" void kernel_launch(void* const* d_in, const int* in_sizes, int n_in,
                              void* d_out, int out_size, void* d_ws, size_t ws_size,
                              hipStream_t stream) {
    const float* pos  = (const float*)d_in[0];
    const int*   sni  = (const int*)  d_in[1];
    const float* w_in = (const float*)d_in[2];
    const float* b_in = (const float*)d_in[3];
    const float* w1   = (const float*)d_in[4];
    const float* b1   = (const float*)d_in[5];
    const float* w2   = (const float*)d_in[6];
    const float* b2   = (const float*)d_in[7];
    float* out = (float*)d_out;
    (void)d_ws; (void)ws_size; (void)in_sizes; (void)n_in; (void)out_size;

    dim3 grid(BB * SS), block(NTH);
    hipLaunchKernelGGL(snp_kernel, grid, block, 0, stream,
                       pos, sni, w_in, b_in, w1, b1, w2, b2, out);
}

// Round 7
// 103.121 us; speedup vs baseline: 2.7682x; 2.7682x over previous
//
#include <hip/hip_runtime.h>
#include <hip/hip_bf16.h>
#include <math.h>

#define BB   2
#define NN   8192
#define SS   1024
#define KK   32
#define HID  256
#define NTH  256
#define PPT  32        // candidates per thread (NN/NTH)
#define SENT 0xFFFFFFFFFFFFFFFFULL
#define LDW  260       // padded LDS row stride (floats); 260%32=4 -> frag reads spread banks
#define WFE  65536     // frag elements per matrix copy (256*256)

typedef unsigned long long u64;
typedef unsigned int       u32;
typedef short bf16x8 __attribute__((ext_vector_type(8)));
typedef float f32x4  __attribute__((ext_vector_type(4)));

// sorted-8 insertion: compare-swap carry chain (keeps s0..s7 ascending, drops max)
#define CSW(SI) { const u64 mn = x < (SI) ? x : (SI); const u64 mx = x < (SI) ? (SI) : x; (SI) = mn; x = mx; }
#define INS(KV) { u64 x = (KV); CSW(s0) CSW(s1) CSW(s2) CSW(s3) CSW(s4) CSW(s5) CSW(s6) CSW(s7) }

// tanh via hardware exp/rcp: tanh(y) = 1 - 2/(1+e^{2y}); saturates correctly.
__device__ __forceinline__ float tanh_fast(float y) {
    const float e = __expf(2.0f * y);
    const float r = __builtin_amdgcn_rcpf(e + 1.0f);
    return fmaf(-2.0f, r, 1.0f);
}

__device__ __forceinline__ short bf_bits(float f) {
    const __hip_bfloat16 h = __float2bfloat16(f);   // RNE
    short s;
    __builtin_memcpy(&s, &h, 2);
    return s;
}

// ---- prep: split w1/w2 into bf16 hi+lo, packed in MFMA B-fragment order ----
// slot e = [ntg:16][ks:8][lane:64][j:8]; element = W[k][n] with
// k = ks*32 + (lane>>4)*8 + j, n = ntg*16 + (lane&15)  (same k-map as A-frags)
__global__ void prep_w(const float* __restrict__ w1, const float* __restrict__ w2,
                       __hip_bfloat16* __restrict__ wf) {
    const int idx = blockIdx.x * 256 + threadIdx.x;   // 0..131071
    const int mat = idx >> 16;
    const int e   = idx & (WFE - 1);
    const int j   = e & 7;
    const int l   = (e >> 3) & 63;
    const int ks  = (e >> 9) & 7;
    const int ntg = e >> 12;
    const int k = ks * 32 + (l >> 4) * 8 + j;
    const int n = ntg * 16 + (l & 15);
    const float v = (mat ? w2 : w1)[k * HID + n];
    const __hip_bfloat16 hi = __float2bfloat16(v);
    const float res = v - __bfloat162float(hi);
    wf[(size_t)mat * 2 * WFE + e]       = hi;
    wf[(size_t)mat * 2 * WFE + WFE + e] = __float2bfloat16(res);
}

__global__ __launch_bounds__(NTH, 4)
void snp_kernel(const float* __restrict__ pos,     // (B,N,3)
                const int*   __restrict__ snidx,   // (S,)
                const float* __restrict__ w_in,    // (3,HID)
                const float* __restrict__ b_in,    // (HID,)
                const float* __restrict__ b1,      // (HID,)
                const float* __restrict__ b2,      // (HID,)
                const __hip_bfloat16* __restrict__ wf,  // frag-packed w1/w2 hi+lo
                float*       __restrict__ out)     // (B,S,HID)
{
    const int bs   = blockIdx.x;        // 0 .. B*S-1
    const int b    = bs / SS;
    const int s    = bs - b * SS;
    const int t    = threadIdx.x;
    const int lane = t & 63;
    const int wv   = t >> 6;

    // 33280 B LDS (padded stride) -> 4 blocks/CU with (256,4).
    __shared__ __align__(16) float h0[KK][LDW];
    u64*   wl  = (u64*)&h0[28][0];      // 4 waves x 32 sorted keys (rows 28-29)
    int*   nbr = (int*)&h0[30][0];      // 32 int
    float* nbc = &h0[31][0];            // 96 f32

    const float* posb = pos + (size_t)b * (NN * 3);
    const int   sp = snidx[s];
    const float sx = posb[sp*3 + 0];
    const float sy = posb[sp*3 + 1];
    const float sz = posb[sp*3 + 2];

    // ---- Phase 1: stream distances (reference rounding), per-lane sorted top-8 ----
    u64 s0=SENT,s1=SENT,s2=SENT,s3=SENT,s4=SENT,s5=SENT,s6=SENT,s7=SENT;
#pragma unroll 4
    for (int c = 0; c < PPT; ++c) {
        const int i = c * NTH + t;                 // coalesced across lanes
        const float dx = __fsub_rn(sx, posb[i*3 + 0]);
        const float dy = __fsub_rn(sy, posb[i*3 + 1]);
        const float dz = __fsub_rn(sz, posb[i*3 + 2]);
        const float sq = __fadd_rn(__fadd_rn(__fmul_rn(dx,dx), __fmul_rn(dy,dy)),
                                   __fmul_rn(dz,dz));
        const u64 kv = ((u64)__float_as_uint(__fsqrt_rn(sq)) << 32) | (u32)i;
        INS(kv);
    }
    int nv = 8;

    // ---- Phase 2: wave-local 32 min-extractions, NO barriers ----
#pragma unroll 1
    for (int it = 0; it < KK; ++it) {
        u64 m = s0;                                 // offer own current min
#pragma unroll
        for (int off = 32; off > 0; off >>= 1) {
            const u64 o = __shfl_xor(m, off, 64);
            m = o < m ? o : m;
        }
        if (lane == 0) wl[wv*KK + it] = m;          // ascending per wave
        if (s0 == m) {                              // unique owner (idx in key)
            s0=s1; s1=s2; s2=s3; s3=s4; s4=s5; s5=s6; s6=s7; s7=SENT;
            if (--nv == 0) {                        // cold: lane owned 8 of wave top-32
                const u64 last = m;
                s0=s1=s2=s3=s4=s5=s6=s7=SENT;
#pragma unroll 4
                for (int c = 0; c < PPT; ++c) {
                    const int i = c * NTH + t;
                    const float dx = __fsub_rn(sx, posb[i*3 + 0]);
                    const float dy = __fsub_rn(sy, posb[i*3 + 1]);
                    const float dz = __fsub_rn(sz, posb[i*3 + 2]);
                    const float sq = __fadd_rn(__fadd_rn(__fmul_rn(dx,dx), __fmul_rn(dy,dy)),
                                               __fmul_rn(dz,dz));
                    u64 kv = ((u64)__float_as_uint(__fsqrt_rn(sq)) << 32) | (u32)i;
                    kv = kv > last ? kv : SENT;     // only keys after lastPopped
                    INS(kv);
                }
                nv = (int)(s0!=SENT)+(int)(s1!=SENT)+(int)(s2!=SENT)+(int)(s3!=SENT)
                   + (int)(s4!=SENT)+(int)(s5!=SENT)+(int)(s6!=SENT)+(int)(s7!=SENT);
            }
        }
    }
    __syncthreads();

    // ---- Phase 2b: wave 0 merges 4 sorted lists via bitonic merges ----
    if (t < 64) {
        auto bmerge = [&](u64 x) -> u64 {          // full-asc sort of bitonic seq
#pragma unroll
            for (int off = 32; off > 0; off >>= 1) {
                const u64 p  = __shfl_xor(x, off, 64);
                const u64 mn = x < p ? x : p;
                const u64 mx = x < p ? p : x;
                x = (lane & off) ? mx : mn;
            }
            return x;
        };
        u64 a = (lane < 32) ? wl[lane] : wl[32 + (63 - lane)];       // L0 asc + L1 desc
        a = bmerge(a);                                               // lanes0-31: top32(L0∪L1)
        u64 b2v = (lane < 32) ? wl[64 + lane] : wl[96 + (63 - lane)];// L2 asc + L3 desc
        b2v = bmerge(b2v);                                           // lanes0-31: top32(L2∪L3)
        const u64 sw = __shfl(b2v, 63 - lane, 64);                   // reverse M23
        u64 cf = (lane < 32) ? a : sw;
        cf = bmerge(cf);                                             // global top-32 asc
        if (lane < 32) nbr[lane] = (int)(u32)cf;                     // idx in low bits
    }
    __syncthreads();

    // ---- Phase 3: gather neighbor coords ----
    if (t < KK * 3) {
        nbc[t] = posb[(size_t)nbr[t / 3] * 3 + (t % 3)];
    }
    __syncthreads();

    // ---- Phase 4: h0 = coords @ w_in + b_in + sincos PE (thread = channel) ----
    {
        const int  c     = t;
        const int  dimi  = c / 84;                  // 84 = 2*42 channels per dim
        const int  cc    = c - dimi * 84;
        const bool hasPe = c < 252;
        const bool isCos = cc >= 42;
        const int  f     = isCos ? cc - 42 : cc;
        const float fcoef = (float)(-9.210340371976184 / 41.0);
        const float freqv = expf((float)f * fcoef);
        const int  di    = hasPe ? dimi : 0;

        const float wi0 = w_in[0*HID + c];
        const float wi1 = w_in[1*HID + c];
        const float wi2 = w_in[2*HID + c];
        const float bi  = b_in[c];

        auto h0val = [&](float x0, float x1, float x2) -> float {
            float v = fmaf(x2, wi2, fmaf(x1, wi1, fmaf(x0, wi0, bi)));
            if (hasPe) {
                const float xv  = (di == 0) ? x0 : ((di == 1) ? x1 : x2);
                const float ang = xv * freqv;
                v += isCos ? __cosf(ang) : __sinf(ang);   // native (args |x|<~6)
            }
            return v;
        };

        // rows 0..30: row 31 (nbc) untouched; rows 28-30 scratch is dead now
#pragma unroll 4
        for (int k = 0; k < KK - 1; ++k) {
            const float x0 = nbc[3*k+0], x1 = nbc[3*k+1], x2 = nbc[3*k+2];
            h0[k][c] = h0val(x0, x1, x2);
        }
        // k=31: its coords live where row 31 will be written -> stage via regs
        __syncthreads();
        const float x0 = nbc[93], x1 = nbc[94], x2 = nbc[95];
        __syncthreads();
        h0[KK-1][c] = h0val(x0, x1, x2);
    }
    __syncthreads();

    // ---- MLP via bf16 MFMA, split weights (hi+lo) for ~fp32 accuracy ----
    // Tiles: M=32 (2 mtiles), N=256 (wave owns 4 ntiles = 64 channels), K=256 (8 ksteps).
    // A frag (16x16x32): row = lane&15, k = ks*32 + (lane>>4)*8 + j  (matches prep).
    // C/D: col = lane&15, row = (lane>>4)*4 + reg   [HW-verified m89]
    const int lr = lane & 15;
    const int lg = lane >> 4;
    const int nbase = wv * 64;

    f32x4 acc[2][4];

    // ---- layer 1: h1 = h0 @ w1 + b1 ----
    {
        const __hip_bfloat16* wh = wf;            // w1 hi
        const __hip_bfloat16* wlo = wf + WFE;     // w1 lo
#pragma unroll
        for (int nt = 0; nt < 4; ++nt) {
            const float bias = b1[nbase + nt*16 + lr];
            const f32x4 bv = {bias, bias, bias, bias};
            acc[0][nt] = bv; acc[1][nt] = bv;
        }
#pragma unroll 1
        for (int ks = 0; ks < 8; ++ks) {
            const int k0 = ks * 32 + lg * 8;
            bf16x8 af[2];
#pragma unroll
            for (int mt = 0; mt < 2; ++mt) {
                const float* src = &h0[mt*16 + lr][k0];
                const float4 p = *(const float4*)src;
                const float4 q = *(const float4*)(src + 4);
                bf16x8 a;
                a[0]=bf_bits(p.x); a[1]=bf_bits(p.y); a[2]=bf_bits(p.z); a[3]=bf_bits(p.w);
                a[4]=bf_bits(q.x); a[5]=bf_bits(q.y); a[6]=bf_bits(q.z); a[7]=bf_bits(q.w);
                af[mt] = a;
            }
#pragma unroll
            for (int nt = 0; nt < 4; ++nt) {
                const size_t off = ((size_t)((wv*4 + nt)*8 + ks) * 64 + lane) * 8;
                const bf16x8 bh = *(const bf16x8*)(wh  + off);   // 16B coalesced
                const bf16x8 bl = *(const bf16x8*)(wlo + off);
                acc[0][nt] = __builtin_amdgcn_mfma_f32_16x16x32_bf16(af[0], bh, acc[0][nt], 0,0,0);
                acc[1][nt] = __builtin_amdgcn_mfma_f32_16x16x32_bf16(af[1], bh, acc[1][nt], 0,0,0);
                acc[0][nt] = __builtin_amdgcn_mfma_f32_16x16x32_bf16(af[0], bl, acc[0][nt], 0,0,0);
                acc[1][nt] = __builtin_amdgcn_mfma_f32_16x16x32_bf16(af[1], bl, acc[1][nt], 0,0,0);
            }
        }
    }
    __syncthreads();                                 // all layer-1 h0 reads done

    // gelu (tanh approx) -> h0 (fp32)
    {
        const float kA = 0.7978845608028654f;        // sqrt(2/pi)
#pragma unroll
        for (int mt = 0; mt < 2; ++mt)
#pragma unroll
        for (int nt = 0; nt < 4; ++nt)
#pragma unroll
        for (int r = 0; r < 4; ++r) {
            const float x  = acc[mt][nt][r];
            const float x3 = x * x * x;
            const float tv = tanh_fast(kA * fmaf(0.044715f, x3, x));
            h0[mt*16 + lg*4 + r][nbase + nt*16 + lr] = 0.5f * x * (1.0f + tv);
        }
    }
    __syncthreads();

    // ---- layer 2: g @ w2 (bias+mean folded into epilogue) ----
    {
        const __hip_bfloat16* wh  = wf + 2*WFE;   // w2 hi
        const __hip_bfloat16* wlo = wf + 3*WFE;   // w2 lo
        const f32x4 z = {0.f, 0.f, 0.f, 0.f};
#pragma unroll
        for (int nt = 0; nt < 4; ++nt) { acc[0][nt] = z; acc[1][nt] = z; }
#pragma unroll 1
        for (int ks = 0; ks < 8; ++ks) {
            const int k0 = ks * 32 + lg * 8;
            bf16x8 af[2];
#pragma unroll
            for (int mt = 0; mt < 2; ++mt) {
                const float* src = &h0[mt*16 + lr][k0];
                const float4 p = *(const float4*)src;
                const float4 q = *(const float4*)(src + 4);
                bf16x8 a;
                a[0]=bf_bits(p.x); a[1]=bf_bits(p.y); a[2]=bf_bits(p.z); a[3]=bf_bits(p.w);
                a[4]=bf_bits(q.x); a[5]=bf_bits(q.y); a[6]=bf_bits(q.z); a[7]=bf_bits(q.w);
                af[mt] = a;
            }
#pragma unroll
            for (int nt = 0; nt < 4; ++nt) {
                const size_t off = ((size_t)((wv*4 + nt)*8 + ks) * 64 + lane) * 8;
                const bf16x8 bh = *(const bf16x8*)(wh  + off);
                const bf16x8 bl = *(const bf16x8*)(wlo + off);
                acc[0][nt] = __builtin_amdgcn_mfma_f32_16x16x32_bf16(af[0], bh, acc[0][nt], 0,0,0);
                acc[1][nt] = __builtin_amdgcn_mfma_f32_16x16x32_bf16(af[1], bh, acc[1][nt], 0,0,0);
                acc[0][nt] = __builtin_amdgcn_mfma_f32_16x16x32_bf16(af[0], bl, acc[0][nt], 0,0,0);
                acc[1][nt] = __builtin_amdgcn_mfma_f32_16x16x32_bf16(af[1], bl, acc[1][nt], 0,0,0);
            }
        }
    }

    // ---- epilogue: mean over 32 rows + b2; lanes<16 write the wave's 64 channels ----
#pragma unroll
    for (int nt = 0; nt < 4; ++nt) {
        float ssum = 0.0f;
#pragma unroll
        for (int mt = 0; mt < 2; ++mt)
#pragma unroll
            for (int r = 0; r < 4; ++r) ssum += acc[mt][nt][r];
        ssum += __shfl_xor(ssum, 16, 64);            // sum over lane-groups
        ssum += __shfl_xor(ssum, 32, 64);
        if (lane < 16) {
            const int ch = nbase + nt*16 + lane;
            out[(size_t)bs * HID + ch] = fmaf(ssum, 1.0f / KK, b2[ch]);
        }
    }
}

extern "C" void kernel_launch(void* const* d_in, const int* in_sizes, int n_in,
                              void* d_out, int out_size, void* d_ws, size_t ws_size,
                              hipStream_t stream) {
    const float* pos  = (const float*)d_in[0];
    const int*   sni  = (const int*)  d_in[1];
    const float* w_in = (const float*)d_in[2];
    const float* b_in = (const float*)d_in[3];
    const float* w1   = (const float*)d_in[4];
    const float* b1   = (const float*)d_in[5];
    const float* w2   = (const float*)d_in[6];
    const float* b2   = (const float*)d_in[7];
    float* out = (float*)d_out;
    __hip_bfloat16* wf = (__hip_bfloat16*)d_ws;      // 4*65536*2B = 512 KB
    (void)ws_size; (void)in_sizes; (void)n_in; (void)out_size;

    hipLaunchKernelGGL(prep_w, dim3(2 * WFE / 256), dim3(256), 0, stream, w1, w2, wf);
    hipLaunchKernelGGL(snp_kernel, dim3(BB * SS), dim3(NTH), 0, stream,
                       pos, sni, w_in, b_in, b1, b2, wf, out);
}

// Round 8
// 97.310 us; speedup vs baseline: 2.9335x; 1.0597x over previous
//
#include <hip/hip_runtime.h>
#include <hip/hip_bf16.h>
#include <math.h>

#define BB   2
#define NN   8192
#define SS   1024
#define KK   32
#define HID  256
#define NTH  256
#define PPT  32        // candidates per thread (NN/NTH)
#define SENT 0xFFFFFFFFFFFFFFFFULL
#define LDB  264       // padded LDS row stride (bf16 elems); 264*2B=528B = 132 dwords (≡4 mod 32)
#define WFE  65536     // frag elements per matrix copy (256*256)

typedef unsigned long long u64;
typedef unsigned int       u32;
typedef short bf16x8 __attribute__((ext_vector_type(8)));
typedef float f32x4  __attribute__((ext_vector_type(4)));

// sorted-8 insertion: compare-swap carry chain (keeps s0..s7 ascending, drops max)
#define CSW(SI) { const u64 mn = x < (SI) ? x : (SI); const u64 mx = x < (SI) ? (SI) : x; (SI) = mn; x = mx; }
#define INS(KV) { u64 x = (KV); CSW(s0) CSW(s1) CSW(s2) CSW(s3) CSW(s4) CSW(s5) CSW(s6) CSW(s7) }

// tanh via hardware exp/rcp: tanh(y) = 1 - 2/(1+e^{2y}); saturates correctly.
__device__ __forceinline__ float tanh_fast(float y) {
    const float e = __expf(2.0f * y);
    const float r = __builtin_amdgcn_rcpf(e + 1.0f);
    return fmaf(-2.0f, r, 1.0f);
}

__device__ __forceinline__ short bf_bits(float f) {
    const __hip_bfloat16 h = __float2bfloat16(f);   // RNE
    short s;
    __builtin_memcpy(&s, &h, 2);
    return s;
}

// ---- prep: split w1/w2 into bf16 hi+lo, packed in MFMA B-fragment order ----
// slot e = [ntg:16][ks:8][lane:64][j:8]; element = W[k][n] with
// k = ks*32 + (lane>>4)*8 + j, n = ntg*16 + (lane&15)  (same k-map as A-frags)
__global__ void prep_w(const float* __restrict__ w1, const float* __restrict__ w2,
                       __hip_bfloat16* __restrict__ wf) {
    const int idx = blockIdx.x * 256 + threadIdx.x;   // 0..131071
    const int mat = idx >> 16;
    const int e   = idx & (WFE - 1);
    const int j   = e & 7;
    const int l   = (e >> 3) & 63;
    const int ks  = (e >> 9) & 7;
    const int ntg = e >> 12;
    const int k = ks * 32 + (l >> 4) * 8 + j;
    const int n = ntg * 16 + (l & 15);
    const float v = (mat ? w2 : w1)[k * HID + n];
    const __hip_bfloat16 hi = __float2bfloat16(v);
    const float res = v - __bfloat162float(hi);
    wf[(size_t)mat * 2 * WFE + e]       = hi;
    wf[(size_t)mat * 2 * WFE + WFE + e] = __float2bfloat16(res);
}

__global__ __launch_bounds__(NTH, 8)
void snp_kernel(const float* __restrict__ pos,     // (B,N,3)
                const int*   __restrict__ snidx,   // (S,)
                const float* __restrict__ w_in,    // (3,HID)
                const float* __restrict__ b_in,    // (HID,)
                const float* __restrict__ b1,      // (HID,)
                const float* __restrict__ b2,      // (HID,)
                const __hip_bfloat16* __restrict__ wf,  // frag-packed w1/w2 hi+lo
                float*       __restrict__ out)     // (B,S,HID)
{
    const int bs   = blockIdx.x;        // 0 .. B*S-1
    const int b    = bs / SS;
    const int s    = bs - b * SS;
    const int t    = threadIdx.x;
    const int lane = t & 63;
    const int wv   = t >> 6;

    // 18432 B LDS total -> 8 blocks/CU (with VGPR <= 64 via launch_bounds).
    __shared__ __align__(16) short h0b[KK][LDB];   // bf16 activations (16896 B)
    __shared__ u64   wl[4 * KK];                   // 4 waves x 32 sorted keys
    __shared__ int   nbr[KK];
    __shared__ float nbc[3 * KK];

    const float* posb = pos + (size_t)b * (NN * 3);
    const int   sp = snidx[s];
    const float sx = posb[sp*3 + 0];
    const float sy = posb[sp*3 + 1];
    const float sz = posb[sp*3 + 2];

    // ---- Phase 1: stream distances (reference rounding), per-lane sorted top-8 ----
    u64 s0=SENT,s1=SENT,s2=SENT,s3=SENT,s4=SENT,s5=SENT,s6=SENT,s7=SENT;
#pragma unroll 4
    for (int c = 0; c < PPT; ++c) {
        const int i = c * NTH + t;                 // coalesced across lanes
        const float dx = __fsub_rn(sx, posb[i*3 + 0]);
        const float dy = __fsub_rn(sy, posb[i*3 + 1]);
        const float dz = __fsub_rn(sz, posb[i*3 + 2]);
        const float sq = __fadd_rn(__fadd_rn(__fmul_rn(dx,dx), __fmul_rn(dy,dy)),
                                   __fmul_rn(dz,dz));
        const u64 kv = ((u64)__float_as_uint(__fsqrt_rn(sq)) << 32) | (u32)i;
        INS(kv);
    }
    int nv = 8;

    // ---- Phase 2: wave-local 32 min-extractions, NO barriers ----
#pragma unroll 1
    for (int it = 0; it < KK; ++it) {
        u64 m = s0;                                 // offer own current min
#pragma unroll
        for (int off = 32; off > 0; off >>= 1) {
            const u64 o = __shfl_xor(m, off, 64);
            m = o < m ? o : m;
        }
        if (lane == 0) wl[wv*KK + it] = m;          // ascending per wave
        if (s0 == m) {                              // unique owner (idx in key)
            s0=s1; s1=s2; s2=s3; s3=s4; s4=s5; s5=s6; s6=s7; s7=SENT;
            if (--nv == 0) {                        // cold: lane owned 8 of wave top-32
                const u64 last = m;
                s0=s1=s2=s3=s4=s5=s6=s7=SENT;
#pragma unroll 4
                for (int c = 0; c < PPT; ++c) {
                    const int i = c * NTH + t;
                    const float dx = __fsub_rn(sx, posb[i*3 + 0]);
                    const float dy = __fsub_rn(sy, posb[i*3 + 1]);
                    const float dz = __fsub_rn(sz, posb[i*3 + 2]);
                    const float sq = __fadd_rn(__fadd_rn(__fmul_rn(dx,dx), __fmul_rn(dy,dy)),
                                               __fmul_rn(dz,dz));
                    u64 kv = ((u64)__float_as_uint(__fsqrt_rn(sq)) << 32) | (u32)i;
                    kv = kv > last ? kv : SENT;     // only keys after lastPopped
                    INS(kv);
                }
                nv = (int)(s0!=SENT)+(int)(s1!=SENT)+(int)(s2!=SENT)+(int)(s3!=SENT)
                   + (int)(s4!=SENT)+(int)(s5!=SENT)+(int)(s6!=SENT)+(int)(s7!=SENT);
            }
        }
    }
    __syncthreads();

    // ---- Phase 2b: wave 0 merges 4 sorted lists via bitonic merges ----
    if (t < 64) {
        auto bmerge = [&](u64 x) -> u64 {          // full-asc sort of bitonic seq
#pragma unroll
            for (int off = 32; off > 0; off >>= 1) {
                const u64 p  = __shfl_xor(x, off, 64);
                const u64 mn = x < p ? x : p;
                const u64 mx = x < p ? p : x;
                x = (lane & off) ? mx : mn;
            }
            return x;
        };
        u64 a = (lane < 32) ? wl[lane] : wl[32 + (63 - lane)];       // L0 asc + L1 desc
        a = bmerge(a);                                               // lanes0-31: top32(L0∪L1)
        u64 b2v = (lane < 32) ? wl[64 + lane] : wl[96 + (63 - lane)];// L2 asc + L3 desc
        b2v = bmerge(b2v);                                           // lanes0-31: top32(L2∪L3)
        const u64 sw = __shfl(b2v, 63 - lane, 64);                   // reverse M23
        u64 cf = (lane < 32) ? a : sw;
        cf = bmerge(cf);                                             // global top-32 asc
        if (lane < 32) nbr[lane] = (int)(u32)cf;                     // idx in low bits
    }
    __syncthreads();

    // ---- Phase 3: gather neighbor coords ----
    if (t < KK * 3) {
        nbc[t] = posb[(size_t)nbr[t / 3] * 3 + (t % 3)];
    }
    __syncthreads();

    // ---- Phase 4: h0 = coords @ w_in + b_in + sincos PE -> bf16 (thread = channel) ----
    // RNE-round at write; identical numerics to rounding at MFMA-read time.
    {
        const int  c     = t;
        const int  dimi  = c / 84;                  // 84 = 2*42 channels per dim
        const int  cc    = c - dimi * 84;
        const bool hasPe = c < 252;
        const bool isCos = cc >= 42;
        const int  f     = isCos ? cc - 42 : cc;
        const float fcoef = (float)(-9.210340371976184 / 41.0);
        const float freqv = expf((float)f * fcoef);
        const int  di    = hasPe ? dimi : 0;

        const float wi0 = w_in[0*HID + c];
        const float wi1 = w_in[1*HID + c];
        const float wi2 = w_in[2*HID + c];
        const float bi  = b_in[c];

#pragma unroll 4
        for (int k = 0; k < KK; ++k) {
            const float x0 = nbc[3*k+0], x1 = nbc[3*k+1], x2 = nbc[3*k+2];
            float v = fmaf(x2, wi2, fmaf(x1, wi1, fmaf(x0, wi0, bi)));
            if (hasPe) {
                const float xv  = (di == 0) ? x0 : ((di == 1) ? x1 : x2);
                const float ang = xv * freqv;
                v += isCos ? __cosf(ang) : __sinf(ang);   // native (args |x|<~6)
            }
            h0b[k][c] = bf_bits(v);
        }
    }
    __syncthreads();

    // ---- MLP via bf16 MFMA, split weights (hi+lo) for ~fp32 accuracy ----
    // Tiles: M=32 (2 mtiles), N=256 (wave owns 4 ntiles = 64 channels), K=256 (8 ksteps).
    // A frag (16x16x32): row = lane&15, k = ks*32 + (lane>>4)*8 + j  (matches prep).
    // C/D: col = lane&15, row = (lane>>4)*4 + reg   [HW-verified m89]
    const int lr = lane & 15;
    const int lg = lane >> 4;
    const int nbase = wv * 64;

    f32x4 acc[2][4];

    // ---- layer 1: h1 = h0 @ w1 + b1 ----
    {
        const __hip_bfloat16* wh  = wf;           // w1 hi
        const __hip_bfloat16* wlo = wf + WFE;     // w1 lo
#pragma unroll
        for (int nt = 0; nt < 4; ++nt) {
            const float bias = b1[nbase + nt*16 + lr];
            const f32x4 bv = {bias, bias, bias, bias};
            acc[0][nt] = bv; acc[1][nt] = bv;
        }
#pragma unroll 1
        for (int ks = 0; ks < 8; ++ks) {
            const int k0 = ks * 32 + lg * 8;
            const bf16x8 af0 = *(const bf16x8*)&h0b[lr][k0];       // direct bf16 A-frags
            const bf16x8 af1 = *(const bf16x8*)&h0b[16 + lr][k0];
#pragma unroll
            for (int nt = 0; nt < 4; ++nt) {
                const size_t off = ((size_t)((wv*4 + nt)*8 + ks) * 64 + lane) * 8;
                {
                    const bf16x8 bh = *(const bf16x8*)(wh + off);   // 16B coalesced
                    acc[0][nt] = __builtin_amdgcn_mfma_f32_16x16x32_bf16(af0, bh, acc[0][nt], 0,0,0);
                    acc[1][nt] = __builtin_amdgcn_mfma_f32_16x16x32_bf16(af1, bh, acc[1][nt], 0,0,0);
                }
                {
                    const bf16x8 bl = *(const bf16x8*)(wlo + off);
                    acc[0][nt] = __builtin_amdgcn_mfma_f32_16x16x32_bf16(af0, bl, acc[0][nt], 0,0,0);
                    acc[1][nt] = __builtin_amdgcn_mfma_f32_16x16x32_bf16(af1, bl, acc[1][nt], 0,0,0);
                }
            }
        }
    }
    __syncthreads();                                 // all layer-1 h0 reads done

    // gelu (tanh approx) -> h0b (bf16; same rounding as before)
    {
        const float kA = 0.7978845608028654f;        // sqrt(2/pi)
#pragma unroll
        for (int mt = 0; mt < 2; ++mt)
#pragma unroll
        for (int nt = 0; nt < 4; ++nt)
#pragma unroll
        for (int r = 0; r < 4; ++r) {
            const float x  = acc[mt][nt][r];
            const float x3 = x * x * x;
            const float tv = tanh_fast(kA * fmaf(0.044715f, x3, x));
            h0b[mt*16 + lg*4 + r][nbase + nt*16 + lr] = bf_bits(0.5f * x * (1.0f + tv));
        }
    }
    __syncthreads();

    // ---- layer 2: g @ w2 (bias+mean folded into epilogue) ----
    {
        const __hip_bfloat16* wh  = wf + 2*WFE;   // w2 hi
        const __hip_bfloat16* wlo = wf + 3*WFE;   // w2 lo
        const f32x4 z = {0.f, 0.f, 0.f, 0.f};
#pragma unroll
        for (int nt = 0; nt < 4; ++nt) { acc[0][nt] = z; acc[1][nt] = z; }
#pragma unroll 1
        for (int ks = 0; ks < 8; ++ks) {
            const int k0 = ks * 32 + lg * 8;
            const bf16x8 af0 = *(const bf16x8*)&h0b[lr][k0];
            const bf16x8 af1 = *(const bf16x8*)&h0b[16 + lr][k0];
#pragma unroll
            for (int nt = 0; nt < 4; ++nt) {
                const size_t off = ((size_t)((wv*4 + nt)*8 + ks) * 64 + lane) * 8;
                {
                    const bf16x8 bh = *(const bf16x8*)(wh + off);
                    acc[0][nt] = __builtin_amdgcn_mfma_f32_16x16x32_bf16(af0, bh, acc[0][nt], 0,0,0);
                    acc[1][nt] = __builtin_amdgcn_mfma_f32_16x16x32_bf16(af1, bh, acc[1][nt], 0,0,0);
                }
                {
                    const bf16x8 bl = *(const bf16x8*)(wlo + off);
                    acc[0][nt] = __builtin_amdgcn_mfma_f32_16x16x32_bf16(af0, bl, acc[0][nt], 0,0,0);
                    acc[1][nt] = __builtin_amdgcn_mfma_f32_16x16x32_bf16(af1, bl, acc[1][nt], 0,0,0);
                }
            }
        }
    }

    // ---- epilogue: mean over 32 rows + b2; lanes<16 write the wave's 64 channels ----
#pragma unroll
    for (int nt = 0; nt < 4; ++nt) {
        float ssum = 0.0f;
#pragma unroll
        for (int mt = 0; mt < 2; ++mt)
#pragma unroll
            for (int r = 0; r < 4; ++r) ssum += acc[mt][nt][r];
        ssum += __shfl_xor(ssum, 16, 64);            // sum over lane-groups
        ssum += __shfl_xor(ssum, 32, 64);
        if (lane < 16) {
            const int ch = nbase + nt*16 + lane;
            out[(size_t)bs * HID + ch] = fmaf(ssum, 1.0f / KK, b2[ch]);
        }
    }
}

extern "C" void kernel_launch(void* const* d_in, const int* in_sizes, int n_in,
                              void* d_out, int out_size, void* d_ws, size_t ws_size,
                              hipStream_t stream) {
    const float* pos  = (const float*)d_in[0];
    const int*   sni  = (const int*)  d_in[1];
    const float* w_in = (const float*)d_in[2];
    const float* b_in = (const float*)d_in[3];
    const float* w1   = (const float*)d_in[4];
    const float* b1   = (const float*)d_in[5];
    const float* w2   = (const float*)d_in[6];
    const float* b2   = (const float*)d_in[7];
    float* out = (float*)d_out;
    __hip_bfloat16* wf = (__hip_bfloat16*)d_ws;      // 4*65536*2B = 512 KB
    (void)ws_size; (void)in_sizes; (void)n_in; (void)out_size;

    hipLaunchKernelGGL(prep_w, dim3(2 * WFE / 256), dim3(256), 0, stream, w1, w2, wf);
    hipLaunchKernelGGL(snp_kernel, dim3(BB * SS), dim3(NTH), 0, stream,
                       pos, sni, w_in, b_in, b1, b2, wf, out);
}

// Round 9
// 94.690 us; speedup vs baseline: 3.0147x; 1.0277x over previous
//
#include <hip/hip_runtime.h>
#include <hip/hip_bf16.h>
#include <math.h>

#define BB   2
#define NN   8192
#define SS   1024
#define KK   32
#define HID  256
#define NTH  256
#define PPT  32        // candidates per thread (NN/NTH)
#define SENT 0xFFFFFFFFFFFFFFFFULL
#define LDB  264       // padded LDS row stride (bf16 elems)
#define WFE  65536     // frag elements per matrix copy (256*256)

typedef unsigned long long u64;
typedef unsigned int       u32;
typedef short bf16x8 __attribute__((ext_vector_type(8)));
typedef float f32x4  __attribute__((ext_vector_type(4)));

// sorted-4 insertion: compare-swap carry chain (keeps s0..s3 ascending, drops max)
#define CSW(SI) { const u64 mn = x < (SI) ? x : (SI); const u64 mx = x < (SI) ? (SI) : x; (SI) = mn; x = mx; }
#define INS(KV) { u64 x = (KV); CSW(s0) CSW(s1) CSW(s2) CSW(s3) }

// tanh via hardware exp/rcp: tanh(y) = 1 - 2/(1+e^{2y}); saturates correctly.
__device__ __forceinline__ float tanh_fast(float y) {
    const float e = __expf(2.0f * y);
    const float r = __builtin_amdgcn_rcpf(e + 1.0f);
    return fmaf(-2.0f, r, 1.0f);
}

__device__ __forceinline__ short bf_bits(float f) {
    const __hip_bfloat16 h = __float2bfloat16(f);   // RNE
    short s;
    __builtin_memcpy(&s, &h, 2);
    return s;
}

// ---- prep: split w1/w2 into bf16 hi+lo, packed in MFMA B-fragment order ----
// slot e = [ntg:16][ks:8][lane:64][j:8]; element = W[k][n] with
// k = ks*32 + (lane>>4)*8 + j, n = ntg*16 + (lane&15)  (same k-map as A-frags)
__global__ void prep_w(const float* __restrict__ w1, const float* __restrict__ w2,
                       __hip_bfloat16* __restrict__ wf) {
    const int idx = blockIdx.x * 256 + threadIdx.x;   // 0..131071
    const int mat = idx >> 16;
    const int e   = idx & (WFE - 1);
    const int j   = e & 7;
    const int l   = (e >> 3) & 63;
    const int ks  = (e >> 9) & 7;
    const int ntg = e >> 12;
    const int k = ks * 32 + (l >> 4) * 8 + j;
    const int n = ntg * 16 + (l & 15);
    const float v = (mat ? w2 : w1)[k * HID + n];
    const __hip_bfloat16 hi = __float2bfloat16(v);
    const float res = v - __bfloat162float(hi);
    wf[(size_t)mat * 2 * WFE + e]       = hi;
    wf[(size_t)mat * 2 * WFE + WFE + e] = __float2bfloat16(res);
}

__global__ __launch_bounds__(NTH, 8)
void snp_kernel(const float* __restrict__ pos,     // (B,N,3)
                const int*   __restrict__ snidx,   // (S,)
                const float* __restrict__ w_in,    // (3,HID)
                const float* __restrict__ b_in,    // (HID,)
                const float* __restrict__ b1,      // (HID,)
                const float* __restrict__ b2,      // (HID,)
                const __hip_bfloat16* __restrict__ wf,  // frag-packed w1/w2 hi+lo
                float*       __restrict__ out)     // (B,S,HID)
{
    const int bs   = blockIdx.x;        // 0 .. B*S-1
    const int b    = bs / SS;
    const int s    = bs - b * SS;
    const int t    = threadIdx.x;
    const int lane = t & 63;
    const int wv   = t >> 6;

    // 18432 B LDS total -> 8 blocks/CU.
    __shared__ __align__(16) short h0b[KK][LDB];   // bf16 activations (16896 B)
    __shared__ u64   wl[4 * KK];                   // 4 waves x 32 sorted keys
    __shared__ int   nbr[KK];
    __shared__ float nbc[3 * KK];

    const float* posb = pos + (size_t)b * (NN * 3);
    const int   sp = snidx[s];
    const float sx = posb[sp*3 + 0];
    const float sy = posb[sp*3 + 1];
    const float sz = posb[sp*3 + 2];

    // ---- Phase 1: stream distances (reference rounding), per-lane sorted top-4 ----
    // Depth-4 suffices unless one lane owns >=5 of its wave's top-32 (P ~ 1.7e-4
    // per lane); the refill path below restores exactness in that case.
    u64 s0=SENT,s1=SENT,s2=SENT,s3=SENT;
#pragma unroll 4
    for (int c = 0; c < PPT; ++c) {
        const int i = c * NTH + t;                 // coalesced across lanes
        const float dx = __fsub_rn(sx, posb[i*3 + 0]);
        const float dy = __fsub_rn(sy, posb[i*3 + 1]);
        const float dz = __fsub_rn(sz, posb[i*3 + 2]);
        const float sq = __fadd_rn(__fadd_rn(__fmul_rn(dx,dx), __fmul_rn(dy,dy)),
                                   __fmul_rn(dz,dz));
        const u64 kv = ((u64)__float_as_uint(__fsqrt_rn(sq)) << 32) | (u32)i;
        INS(kv);
    }
    int nv = 4;

    // ---- Phase 2: wave-local 32 min-extractions, NO barriers ----
#pragma unroll 1
    for (int it = 0; it < KK; ++it) {
        u64 m = s0;                                 // offer own current min
#pragma unroll
        for (int off = 32; off > 0; off >>= 1) {
            const u64 o = __shfl_xor(m, off, 64);
            m = o < m ? o : m;
        }
        if (lane == 0) wl[wv*KK + it] = m;          // ascending per wave
        if (s0 == m) {                              // unique owner (idx in key)
            s0=s1; s1=s2; s2=s3; s3=SENT;
            if (--nv == 0) {                        // cold: lane owned 4 already
                const u64 last = m;                 // pops are ascending per lane
                s0=s1=s2=s3=SENT;
#pragma unroll 4
                for (int c = 0; c < PPT; ++c) {
                    const int i = c * NTH + t;
                    const float dx = __fsub_rn(sx, posb[i*3 + 0]);
                    const float dy = __fsub_rn(sy, posb[i*3 + 1]);
                    const float dz = __fsub_rn(sz, posb[i*3 + 2]);
                    const float sq = __fadd_rn(__fadd_rn(__fmul_rn(dx,dx), __fmul_rn(dy,dy)),
                                               __fmul_rn(dz,dz));
                    u64 kv = ((u64)__float_as_uint(__fsqrt_rn(sq)) << 32) | (u32)i;
                    kv = kv > last ? kv : SENT;     // only keys after lastPopped
                    INS(kv);
                }
                nv = (int)(s0!=SENT)+(int)(s1!=SENT)+(int)(s2!=SENT)+(int)(s3!=SENT);
            }
        }
    }
    __syncthreads();

    // ---- Phase 2b: wave 0 merges 4 sorted lists via bitonic merges ----
    if (t < 64) {
        auto bmerge = [&](u64 x) -> u64 {          // full-asc sort of bitonic seq
#pragma unroll
            for (int off = 32; off > 0; off >>= 1) {
                const u64 p  = __shfl_xor(x, off, 64);
                const u64 mn = x < p ? x : p;
                const u64 mx = x < p ? p : x;
                x = (lane & off) ? mx : mn;
            }
            return x;
        };
        u64 a = (lane < 32) ? wl[lane] : wl[32 + (63 - lane)];       // L0 asc + L1 desc
        a = bmerge(a);                                               // lanes0-31: top32(L0∪L1)
        u64 b2v = (lane < 32) ? wl[64 + lane] : wl[96 + (63 - lane)];// L2 asc + L3 desc
        b2v = bmerge(b2v);                                           // lanes0-31: top32(L2∪L3)
        const u64 sw = __shfl(b2v, 63 - lane, 64);                   // reverse M23
        u64 cf = (lane < 32) ? a : sw;
        cf = bmerge(cf);                                             // global top-32 asc
        if (lane < 32) nbr[lane] = (int)(u32)cf;                     // idx in low bits
    }
    __syncthreads();

    // ---- Phase 3: gather neighbor coords ----
    if (t < KK * 3) {
        nbc[t] = posb[(size_t)nbr[t / 3] * 3 + (t % 3)];
    }
    __syncthreads();

    // ---- Phase 4: h0 = coords @ w_in + b_in + sincos PE -> bf16 (thread = channel) ----
    {
        const int  c     = t;
        const int  dimi  = c / 84;                  // 84 = 2*42 channels per dim
        const int  cc    = c - dimi * 84;
        const bool hasPe = c < 252;
        const bool isCos = cc >= 42;
        const int  f     = isCos ? cc - 42 : cc;
        const float fcoef = (float)(-9.210340371976184 / 41.0);
        const float freqv = expf((float)f * fcoef);
        const int  di    = hasPe ? dimi : 0;

        const float wi0 = w_in[0*HID + c];
        const float wi1 = w_in[1*HID + c];
        const float wi2 = w_in[2*HID + c];
        const float bi  = b_in[c];

#pragma unroll 4
        for (int k = 0; k < KK; ++k) {
            const float x0 = nbc[3*k+0], x1 = nbc[3*k+1], x2 = nbc[3*k+2];
            float v = fmaf(x2, wi2, fmaf(x1, wi1, fmaf(x0, wi0, bi)));
            if (hasPe) {
                const float xv  = (di == 0) ? x0 : ((di == 1) ? x1 : x2);
                const float ang = xv * freqv;
                v += isCos ? __cosf(ang) : __sinf(ang);   // native (args |x|<~6)
            }
            h0b[k][c] = bf_bits(v);
        }
    }
    __syncthreads();

    // ---- MLP via bf16 MFMA, split weights (hi+lo) for ~fp32 accuracy ----
    // Tiles: M=32 (2 mtiles), N=256 (wave owns 4 ntiles = 64 channels), K=256 (8 ksteps).
    // A frag (16x16x32): row = lane&15, k = ks*32 + (lane>>4)*8 + j  (matches prep).
    // C/D: col = lane&15, row = (lane>>4)*4 + reg   [HW-verified m89]
    const int lr = lane & 15;
    const int lg = lane >> 4;
    const int nbase = wv * 64;

    f32x4 acc[2][4];

    // ---- layer 1: h1 = h0 @ w1 + b1 ----
    {
        const __hip_bfloat16* wh  = wf;           // w1 hi
        const __hip_bfloat16* wlo = wf + WFE;     // w1 lo
#pragma unroll
        for (int nt = 0; nt < 4; ++nt) {
            const float bias = b1[nbase + nt*16 + lr];
            const f32x4 bv = {bias, bias, bias, bias};
            acc[0][nt] = bv; acc[1][nt] = bv;
        }
#pragma unroll 1
        for (int ks = 0; ks < 8; ++ks) {
            const int k0 = ks * 32 + lg * 8;
            const bf16x8 af0 = *(const bf16x8*)&h0b[lr][k0];       // direct bf16 A-frags
            const bf16x8 af1 = *(const bf16x8*)&h0b[16 + lr][k0];
#pragma unroll
            for (int nt = 0; nt < 4; ++nt) {
                const size_t off = ((size_t)((wv*4 + nt)*8 + ks) * 64 + lane) * 8;
                {
                    const bf16x8 bh = *(const bf16x8*)(wh + off);   // 16B coalesced
                    acc[0][nt] = __builtin_amdgcn_mfma_f32_16x16x32_bf16(af0, bh, acc[0][nt], 0,0,0);
                    acc[1][nt] = __builtin_amdgcn_mfma_f32_16x16x32_bf16(af1, bh, acc[1][nt], 0,0,0);
                }
                {
                    const bf16x8 bl = *(const bf16x8*)(wlo + off);
                    acc[0][nt] = __builtin_amdgcn_mfma_f32_16x16x32_bf16(af0, bl, acc[0][nt], 0,0,0);
                    acc[1][nt] = __builtin_amdgcn_mfma_f32_16x16x32_bf16(af1, bl, acc[1][nt], 0,0,0);
                }
            }
        }
    }
    __syncthreads();                                 // all layer-1 h0 reads done

    // gelu (tanh approx) -> h0b (bf16; same rounding as before)
    {
        const float kA = 0.7978845608028654f;        // sqrt(2/pi)
#pragma unroll
        for (int mt = 0; mt < 2; ++mt)
#pragma unroll
        for (int nt = 0; nt < 4; ++nt)
#pragma unroll
        for (int r = 0; r < 4; ++r) {
            const float x  = acc[mt][nt][r];
            const float x3 = x * x * x;
            const float tv = tanh_fast(kA * fmaf(0.044715f, x3, x));
            h0b[mt*16 + lg*4 + r][nbase + nt*16 + lr] = bf_bits(0.5f * x * (1.0f + tv));
        }
    }
    __syncthreads();

    // ---- layer 2: g @ w2 (bias+mean folded into epilogue) ----
    {
        const __hip_bfloat16* wh  = wf + 2*WFE;   // w2 hi
        const __hip_bfloat16* wlo = wf + 3*WFE;   // w2 lo
        const f32x4 z = {0.f, 0.f, 0.f, 0.f};
#pragma unroll
        for (int nt = 0; nt < 4; ++nt) { acc[0][nt] = z; acc[1][nt] = z; }
#pragma unroll 1
        for (int ks = 0; ks < 8; ++ks) {
            const int k0 = ks * 32 + lg * 8;
            const bf16x8 af0 = *(const bf16x8*)&h0b[lr][k0];
            const bf16x8 af1 = *(const bf16x8*)&h0b[16 + lr][k0];
#pragma unroll
            for (int nt = 0; nt < 4; ++nt) {
                const size_t off = ((size_t)((wv*4 + nt)*8 + ks) * 64 + lane) * 8;
                {
                    const bf16x8 bh = *(const bf16x8*)(wh + off);
                    acc[0][nt] = __builtin_amdgcn_mfma_f32_16x16x32_bf16(af0, bh, acc[0][nt], 0,0,0);
                    acc[1][nt] = __builtin_amdgcn_mfma_f32_16x16x32_bf16(af1, bh, acc[1][nt], 0,0,0);
                }
                {
                    const bf16x8 bl = *(const bf16x8*)(wlo + off);
                    acc[0][nt] = __builtin_amdgcn_mfma_f32_16x16x32_bf16(af0, bl, acc[0][nt], 0,0,0);
                    acc[1][nt] = __builtin_amdgcn_mfma_f32_16x16x32_bf16(af1, bl, acc[1][nt], 0,0,0);
                }
            }
        }
    }

    // ---- epilogue: mean over 32 rows + b2; lanes<16 write the wave's 64 channels ----
#pragma unroll
    for (int nt = 0; nt < 4; ++nt) {
        float ssum = 0.0f;
#pragma unroll
        for (int mt = 0; mt < 2; ++mt)
#pragma unroll
            for (int r = 0; r < 4; ++r) ssum += acc[mt][nt][r];
        ssum += __shfl_xor(ssum, 16, 64);            // sum over lane-groups
        ssum += __shfl_xor(ssum, 32, 64);
        if (lane < 16) {
            const int ch = nbase + nt*16 + lane;
            out[(size_t)bs * HID + ch] = fmaf(ssum, 1.0f / KK, b2[ch]);
        }
    }
}

extern "C" void kernel_launch(void* const* d_in, const int* in_sizes, int n_in,
                              void* d_out, int out_size, void* d_ws, size_t ws_size,
                              hipStream_t stream) {
    const float* pos  = (const float*)d_in[0];
    const int*   sni  = (const int*)  d_in[1];
    const float* w_in = (const float*)d_in[2];
    const float* b_in = (const float*)d_in[3];
    const float* w1   = (const float*)d_in[4];
    const float* b1   = (const float*)d_in[5];
    const float* w2   = (const float*)d_in[6];
    const float* b2   = (const float*)d_in[7];
    float* out = (float*)d_out;
    __hip_bfloat16* wf = (__hip_bfloat16*)d_ws;      // 4*65536*2B = 512 KB
    (void)ws_size; (void)in_sizes; (void)n_in; (void)out_size;

    hipLaunchKernelGGL(prep_w, dim3(2 * WFE / 256), dim3(256), 0, stream, w1, w2, wf);
    hipLaunchKernelGGL(snp_kernel, dim3(BB * SS), dim3(NTH), 0, stream,
                       pos, sni, w_in, b_in, b1, b2, wf, out);
}

// Round 10
// 88.855 us; speedup vs baseline: 3.2127x; 1.0657x over previous
//
#include <hip/hip_runtime.h>
#include <hip/hip_bf16.h>
#include <math.h>

#define BB   2
#define NN   8192
#define SS   1024
#define KK   32
#define HID  256
#define NTH  256
#define PPT  32        // candidates per thread (NN/NTH)
#define SENT 0xFFFFFFFFFFFFFFFFULL
#define LDB  264       // padded LDS row stride (bf16 elems)
#define WFE  65536     // frag elements per matrix copy (256*256)

typedef unsigned long long u64;
typedef unsigned int       u32;
typedef short bf16x8 __attribute__((ext_vector_type(8)));
typedef float f32x4  __attribute__((ext_vector_type(4)));

// sorted-4 insertion: compare-swap carry chain (keeps s0..s3 ascending, drops max)
#define CSW(SI) { const u64 mn = x < (SI) ? x : (SI); const u64 mx = x < (SI) ? (SI) : x; (SI) = mn; x = mx; }
#define INS(KV) { u64 x = (KV); CSW(s0) CSW(s1) CSW(s2) CSW(s3) }

// tanh via hardware exp/rcp: tanh(y) = 1 - 2/(1+e^{2y}); saturates correctly.
__device__ __forceinline__ float tanh_fast(float y) {
    const float e = __expf(2.0f * y);
    const float r = __builtin_amdgcn_rcpf(e + 1.0f);
    return fmaf(-2.0f, r, 1.0f);
}

__device__ __forceinline__ short bf_bits(float f) {
    const __hip_bfloat16 h = __float2bfloat16(f);   // RNE
    short s;
    __builtin_memcpy(&s, &h, 2);
    return s;
}

// popcount of mask restricted to lanes below me
__device__ __forceinline__ int mbcnt64(u64 m) {
    return (int)__builtin_amdgcn_mbcnt_hi((u32)(m >> 32),
           __builtin_amdgcn_mbcnt_lo((u32)m, 0u));
}

// ---- prep: split w1/w2 into bf16 hi+lo, packed in MFMA B-fragment order ----
__global__ void prep_w(const float* __restrict__ w1, const float* __restrict__ w2,
                       __hip_bfloat16* __restrict__ wf) {
    const int idx = blockIdx.x * 256 + threadIdx.x;   // 0..131071
    const int mat = idx >> 16;
    const int e   = idx & (WFE - 1);
    const int j   = e & 7;
    const int l   = (e >> 3) & 63;
    const int ks  = (e >> 9) & 7;
    const int ntg = e >> 12;
    const int k = ks * 32 + (l >> 4) * 8 + j;
    const int n = ntg * 16 + (l & 15);
    const float v = (mat ? w2 : w1)[k * HID + n];
    const __hip_bfloat16 hi = __float2bfloat16(v);
    const float res = v - __bfloat162float(hi);
    wf[(size_t)mat * 2 * WFE + e]       = hi;
    wf[(size_t)mat * 2 * WFE + WFE + e] = __float2bfloat16(res);
}

__global__ __launch_bounds__(NTH, 8)
void snp_kernel(const float* __restrict__ pos,     // (B,N,3)
                const int*   __restrict__ snidx,   // (S,)
                const float* __restrict__ w_in,    // (3,HID)
                const float* __restrict__ b_in,    // (HID,)
                const float* __restrict__ b1,      // (HID,)
                const float* __restrict__ b2,      // (HID,)
                const __hip_bfloat16* __restrict__ wf,  // frag-packed w1/w2 hi+lo
                float*       __restrict__ out)     // (B,S,HID)
{
    const int bs   = blockIdx.x;        // 0 .. B*S-1
    const int b    = bs / SS;
    const int s    = bs - b * SS;
    const int t    = threadIdx.x;
    const int lane = t & 63;
    const int wv   = t >> 6;

    __shared__ __align__(16) short h0b[KK][LDB];   // bf16 activations (16896 B)
    __shared__ u64   wl[4 * KK];                   // 4 waves x 32 selected keys
    __shared__ int   nbr[KK];
    __shared__ float nbc[3 * KK];

    const float* posb = pos + (size_t)b * (NN * 3);
    const int   sp = snidx[s];
    const float sx = posb[sp*3 + 0];
    const float sy = posb[sp*3 + 1];
    const float sz = posb[sp*3 + 2];

    // ---- Phase 1: stream distances (reference rounding), per-lane sorted top-4 ----
    // Compact key: (distbits << 13) | idx  (idx < 8192) — order == (dist, idx) lex.
    u64 s0=SENT,s1=SENT,s2=SENT,s3=SENT;
#pragma unroll 4
    for (int c = 0; c < PPT; ++c) {
        const int i = c * NTH + t;                 // coalesced across lanes
        const float dx = __fsub_rn(sx, posb[i*3 + 0]);
        const float dy = __fsub_rn(sy, posb[i*3 + 1]);
        const float dz = __fsub_rn(sz, posb[i*3 + 2]);
        const float sq = __fadd_rn(__fadd_rn(__fmul_rn(dx,dx), __fmul_rn(dy,dy)),
                                   __fmul_rn(dz,dz));
        const u64 kv = ((u64)__float_as_uint(__fsqrt_rn(sq)) << 13) | (u32)i;
        INS(kv);
    }

    // ---- Phase 2: wave-level threshold selection (ballot binary search) ----
    // Find largest L (44-bit) with cnt(keys < L) < 32; selected = keys <= L.
    // Distinct keys (idx embedded) => exactly 32 selected, matching stable argsort.
    {
        u64 L = 0;
        for (int bit = 43; bit >= 0; --bit) {
            const u64 cand = L | (1ull << bit);
            const int cnt = __popcll(__ballot(s0 < cand)) + __popcll(__ballot(s1 < cand))
                          + __popcll(__ballot(s2 < cand)) + __popcll(__ballot(s3 < cand));
            if (cnt < 32) L = cand;
        }
        const bool b0 = s0 <= L, b1 = s1 <= L, b2 = s2 <= L, b3 = s3 <= L;
        const int csel = (int)b0 + (int)b1 + (int)b2 + (int)b3;

        if (__ballot(csel == 4) != 0ull) {
            // Saturated lane (may own a hidden 5th key <= L): fall back to the
            // proven serial extraction (R9 logic) for this wave. ~10% of waves.
            int nv = 4;
#pragma unroll 1
            for (int it = 0; it < KK; ++it) {
                u64 m = s0;
#pragma unroll
                for (int off = 32; off > 0; off >>= 1) {
                    const u64 o = __shfl_xor(m, off, 64);
                    m = o < m ? o : m;
                }
                if (lane == 0) wl[wv*KK + it] = m;
                if (s0 == m) {
                    s0=s1; s1=s2; s2=s3; s3=SENT;
                    if (--nv == 0) {                // refill from stream, keys > m
                        const u64 last = m;
                        s0=s1=s2=s3=SENT;
#pragma unroll 4
                        for (int c = 0; c < PPT; ++c) {
                            const int i = c * NTH + t;
                            const float dx = __fsub_rn(sx, posb[i*3 + 0]);
                            const float dy = __fsub_rn(sy, posb[i*3 + 1]);
                            const float dz = __fsub_rn(sz, posb[i*3 + 2]);
                            const float sq = __fadd_rn(__fadd_rn(__fmul_rn(dx,dx), __fmul_rn(dy,dy)),
                                                       __fmul_rn(dz,dz));
                            u64 kv = ((u64)__float_as_uint(__fsqrt_rn(sq)) << 13) | (u32)i;
                            kv = kv > last ? kv : SENT;
                            INS(kv);
                        }
                        nv = (int)(s0!=SENT)+(int)(s1!=SENT)+(int)(s2!=SENT)+(int)(s3!=SENT);
                    }
                }
            }
        } else {
            // Exact-32 fast path: compact selected keys (unsorted — order is
            // irrelevant downstream; output is a mean over k).
            const u64 m0 = __ballot(b0), m1 = __ballot(b1),
                      m2 = __ballot(b2), m3 = __ballot(b3);
            const int pos = mbcnt64(m0) + mbcnt64(m1) + mbcnt64(m2) + mbcnt64(m3);
            u64* wwl = &wl[wv * KK];
            if (b0) wwl[pos]     = s0;
            if (b1) wwl[pos + 1] = s1;
            if (b2) wwl[pos + 2] = s2;
            if (b3) wwl[pos + 3] = s3;
        }
    }
    __syncthreads();

    // ---- Phase 2b: block stage — top-32 of the 128 wave-selected keys ----
    if (t < 64) {
        const u64 k0 = wl[lane], k1 = wl[64 + lane];   // 2 keys/lane, fully known
        u64 L = 0;
        for (int bit = 43; bit >= 0; --bit) {
            const u64 cand = L | (1ull << bit);
            const int cnt = __popcll(__ballot(k0 < cand)) + __popcll(__ballot(k1 < cand));
            if (cnt < 32) L = cand;
        }
        const bool c0 = k0 <= L, c1 = k1 <= L;
        const int p = mbcnt64(__ballot(c0)) + mbcnt64(__ballot(c1));
        if (c0) nbr[p]            = (int)(k0 & 8191u);
        if (c1) nbr[p + (int)c0]  = (int)(k1 & 8191u);
    }
    __syncthreads();

    // ---- Phase 3: gather neighbor coords ----
    if (t < KK * 3) {
        nbc[t] = posb[(size_t)nbr[t / 3] * 3 + (t % 3)];
    }
    __syncthreads();

    // ---- Phase 4: h0 = coords @ w_in + b_in + sincos PE -> bf16 (thread = channel) ----
    {
        const int  c     = t;
        const int  dimi  = c / 84;                  // 84 = 2*42 channels per dim
        const int  cc    = c - dimi * 84;
        const bool hasPe = c < 252;
        const bool isCos = cc >= 42;
        const int  f     = isCos ? cc - 42 : cc;
        const float fcoef = (float)(-9.210340371976184 / 41.0);
        const float freqv = expf((float)f * fcoef);
        const int  di    = hasPe ? dimi : 0;

        const float wi0 = w_in[0*HID + c];
        const float wi1 = w_in[1*HID + c];
        const float wi2 = w_in[2*HID + c];
        const float bi  = b_in[c];

#pragma unroll 4
        for (int k = 0; k < KK; ++k) {
            const float x0 = nbc[3*k+0], x1 = nbc[3*k+1], x2 = nbc[3*k+2];
            float v = fmaf(x2, wi2, fmaf(x1, wi1, fmaf(x0, wi0, bi)));
            if (hasPe) {
                const float xv  = (di == 0) ? x0 : ((di == 1) ? x1 : x2);
                const float ang = xv * freqv;
                v += isCos ? __cosf(ang) : __sinf(ang);   // native (args |x|<~6)
            }
            h0b[k][c] = bf_bits(v);
        }
    }
    __syncthreads();

    // ---- MLP via bf16 MFMA, split weights (hi+lo) for ~fp32 accuracy ----
    // A frag (16x16x32): row = lane&15, k = ks*32 + (lane>>4)*8 + j  (matches prep).
    // C/D: col = lane&15, row = (lane>>4)*4 + reg   [HW-verified m89]
    const int lr = lane & 15;
    const int lg = lane >> 4;
    const int nbase = wv * 64;

    f32x4 acc[2][4];

    // ---- layer 1: h1 = h0 @ w1 + b1 ----
    {
        const __hip_bfloat16* wh  = wf;           // w1 hi
        const __hip_bfloat16* wlo = wf + WFE;     // w1 lo
#pragma unroll
        for (int nt = 0; nt < 4; ++nt) {
            const float bias = b1[nbase + nt*16 + lr];
            const f32x4 bv = {bias, bias, bias, bias};
            acc[0][nt] = bv; acc[1][nt] = bv;
        }
#pragma unroll 1
        for (int ks = 0; ks < 8; ++ks) {
            const int k0 = ks * 32 + lg * 8;
            const bf16x8 af0 = *(const bf16x8*)&h0b[lr][k0];       // direct bf16 A-frags
            const bf16x8 af1 = *(const bf16x8*)&h0b[16 + lr][k0];
#pragma unroll
            for (int nt = 0; nt < 4; ++nt) {
                const size_t off = ((size_t)((wv*4 + nt)*8 + ks) * 64 + lane) * 8;
                {
                    const bf16x8 bh = *(const bf16x8*)(wh + off);   // 16B coalesced
                    acc[0][nt] = __builtin_amdgcn_mfma_f32_16x16x32_bf16(af0, bh, acc[0][nt], 0,0,0);
                    acc[1][nt] = __builtin_amdgcn_mfma_f32_16x16x32_bf16(af1, bh, acc[1][nt], 0,0,0);
                }
                {
                    const bf16x8 bl = *(const bf16x8*)(wlo + off);
                    acc[0][nt] = __builtin_amdgcn_mfma_f32_16x16x32_bf16(af0, bl, acc[0][nt], 0,0,0);
                    acc[1][nt] = __builtin_amdgcn_mfma_f32_16x16x32_bf16(af1, bl, acc[1][nt], 0,0,0);
                }
            }
        }
    }
    __syncthreads();                                 // all layer-1 h0 reads done

    // gelu (tanh approx) -> h0b (bf16; same rounding as before)
    {
        const float kA = 0.7978845608028654f;        // sqrt(2/pi)
#pragma unroll
        for (int mt = 0; mt < 2; ++mt)
#pragma unroll
        for (int nt = 0; nt < 4; ++nt)
#pragma unroll
        for (int r = 0; r < 4; ++r) {
            const float x  = acc[mt][nt][r];
            const float x3 = x * x * x;
            const float tv = tanh_fast(kA * fmaf(0.044715f, x3, x));
            h0b[mt*16 + lg*4 + r][nbase + nt*16 + lr] = bf_bits(0.5f * x * (1.0f + tv));
        }
    }
    __syncthreads();

    // ---- layer 2: g @ w2 (bias+mean folded into epilogue) ----
    {
        const __hip_bfloat16* wh  = wf + 2*WFE;   // w2 hi
        const __hip_bfloat16* wlo = wf + 3*WFE;   // w2 lo
        const f32x4 z = {0.f, 0.f, 0.f, 0.f};
#pragma unroll
        for (int nt = 0; nt < 4; ++nt) { acc[0][nt] = z; acc[1][nt] = z; }
#pragma unroll 1
        for (int ks = 0; ks < 8; ++ks) {
            const int k0 = ks * 32 + lg * 8;
            const bf16x8 af0 = *(const bf16x8*)&h0b[lr][k0];
            const bf16x8 af1 = *(const bf16x8*)&h0b[16 + lr][k0];
#pragma unroll
            for (int nt = 0; nt < 4; ++nt) {
                const size_t off = ((size_t)((wv*4 + nt)*8 + ks) * 64 + lane) * 8;
                {
                    const bf16x8 bh = *(const bf16x8*)(wh + off);
                    acc[0][nt] = __builtin_amdgcn_mfma_f32_16x16x32_bf16(af0, bh, acc[0][nt], 0,0,0);
                    acc[1][nt] = __builtin_amdgcn_mfma_f32_16x16x32_bf16(af1, bh, acc[1][nt], 0,0,0);
                }
                {
                    const bf16x8 bl = *(const bf16x8*)(wlo + off);
                    acc[0][nt] = __builtin_amdgcn_mfma_f32_16x16x32_bf16(af0, bl, acc[0][nt], 0,0,0);
                    acc[1][nt] = __builtin_amdgcn_mfma_f32_16x16x32_bf16(af1, bl, acc[1][nt], 0,0,0);
                }
            }
        }
    }

    // ---- epilogue: mean over 32 rows + b2; lanes<16 write the wave's 64 channels ----
#pragma unroll
    for (int nt = 0; nt < 4; ++nt) {
        float ssum = 0.0f;
#pragma unroll
        for (int mt = 0; mt < 2; ++mt)
#pragma unroll
            for (int r = 0; r < 4; ++r) ssum += acc[mt][nt][r];
        ssum += __shfl_xor(ssum, 16, 64);            // sum over lane-groups
        ssum += __shfl_xor(ssum, 32, 64);
        if (lane < 16) {
            const int ch = nbase + nt*16 + lane;
            out[(size_t)bs * HID + ch] = fmaf(ssum, 1.0f / KK, b2[ch]);
        }
    }
}

extern "C" void kernel_launch(void* const* d_in, const int* in_sizes, int n_in,
                              void* d_out, int out_size, void* d_ws, size_t ws_size,
                              hipStream_t stream) {
    const float* pos  = (const float*)d_in[0];
    const int*   sni  = (const int*)  d_in[1];
    const float* w_in = (const float*)d_in[2];
    const float* b_in = (const float*)d_in[3];
    const float* w1   = (const float*)d_in[4];
    const float* b1   = (const float*)d_in[5];
    const float* w2   = (const float*)d_in[6];
    const float* b2   = (const float*)d_in[7];
    float* out = (float*)d_out;
    __hip_bfloat16* wf = (__hip_bfloat16*)d_ws;      // 4*65536*2B = 512 KB
    (void)ws_size; (void)in_sizes; (void)n_in; (void)out_size;

    hipLaunchKernelGGL(prep_w, dim3(2 * WFE / 256), dim3(256), 0, stream, w1, w2, wf);
    hipLaunchKernelGGL(snp_kernel, dim3(BB * SS), dim3(NTH), 0, stream,
                       pos, sni, w_in, b_in, b1, b2, wf, out);
}

// Round 11
// 86.569 us; speedup vs baseline: 3.2975x; 1.0264x over previous
//
#include <hip/hip_runtime.h>
#include <hip/hip_bf16.h>
#include <math.h>

#define BB   2
#define NN   8192
#define SS   1024
#define KK   32
#define HID  256
#define NTH  256
#define PPT  32        // candidates per thread (NN/NTH)
#define SENT 0xFFFFFFFFFFFFFFFFULL
#define LDB  264       // padded LDS row stride (bf16 elems)
#define WFE  65536     // frag elements per matrix copy (256*256)

typedef unsigned long long u64;
typedef unsigned int       u32;
typedef short bf16x8 __attribute__((ext_vector_type(8)));
typedef float f32x4  __attribute__((ext_vector_type(4)));

// sorted-4 insertion: compare-swap carry chain (keeps s0..s3 ascending, drops max)
#define CSW(SI) { const u64 mn = x < (SI) ? x : (SI); const u64 mx = x < (SI) ? (SI) : x; (SI) = mn; x = mx; }
#define INS(KV) { u64 x = (KV); CSW(s0) CSW(s1) CSW(s2) CSW(s3) }

// tanh via hardware exp/rcp: tanh(y) = 1 - 2/(1+e^{2y}); saturates correctly.
__device__ __forceinline__ float tanh_fast(float y) {
    const float e = __expf(2.0f * y);
    const float r = __builtin_amdgcn_rcpf(e + 1.0f);
    return fmaf(-2.0f, r, 1.0f);
}

__device__ __forceinline__ short bf_bits(float f) {
    const __hip_bfloat16 h = __float2bfloat16(f);   // RNE
    short s;
    __builtin_memcpy(&s, &h, 2);
    return s;
}

// popcount of mask restricted to lanes below me
__device__ __forceinline__ int mbcnt64(u64 m) {
    return (int)__builtin_amdgcn_mbcnt_hi((u32)(m >> 32),
           __builtin_amdgcn_mbcnt_lo((u32)m, 0u));
}

// ---- prep: split w1/w2 into bf16 hi+lo, MFMA B-frag order, ks-major grouping ----
// elem slot = mat*131072 + (((ks*16+ntg)*2+hl)*64+lane)*8 + j
// element  = W[k][n], k = ks*32 + (lane>>4)*8 + j, n = ntg*16 + (lane&15)
__global__ void prep_w(const float* __restrict__ w1, const float* __restrict__ w2,
                       __hip_bfloat16* __restrict__ wf) {
    const int idx = blockIdx.x * 256 + threadIdx.x;   // 0..131071
    const int j   = idx & 7;
    const int l   = (idx >> 3) & 63;
    const int ntg = (idx >> 9) & 15;
    const int ks  = (idx >> 13) & 7;
    const int mat = idx >> 16;
    const int k = ks * 32 + (l >> 4) * 8 + j;
    const int n = ntg * 16 + (l & 15);
    const float v = (mat ? w2 : w1)[k * HID + n];
    const __hip_bfloat16 hi = __float2bfloat16(v);
    const float res = v - __bfloat162float(hi);
    const size_t s0 = (size_t)mat * 131072 + ((size_t)((ks*16 + ntg)*2) * 64 + l) * 8 + j;
    wf[s0]       = hi;
    wf[s0 + 512] = __float2bfloat16(res);            // hl=1 slot
}

__global__ __launch_bounds__(NTH, 8)
void snp_kernel(const float* __restrict__ pos,     // (B,N,3)
                const int*   __restrict__ snidx,   // (S,)
                const float* __restrict__ w_in,    // (3,HID)
                const float* __restrict__ b_in,    // (HID,)
                const float* __restrict__ b1,      // (HID,)
                const float* __restrict__ b2,      // (HID,)
                const __hip_bfloat16* __restrict__ wf,  // frag-packed w1/w2 hi+lo
                float*       __restrict__ out)     // (B,S,HID)
{
    const int bs   = blockIdx.x;        // 0 .. B*S-1
    const int b    = bs / SS;
    const int s    = bs - b * SS;
    const int t    = threadIdx.x;
    const int lane = t & 63;
    const int wv   = t >> 6;

    __shared__ __align__(16) short h0b[KK][LDB];   // bf16 activations (16896 B)
    __shared__ u64   wl[4 * KK];                   // 4 waves x 32 selected keys
    __shared__ int   nbr[KK];
    __shared__ __align__(16) float nbc[4 * KK];    // float4-strided coords

    const float* posb = pos + (size_t)b * (NN * 3);
    const int   sp = snidx[s];
    const float sx = posb[sp*3 + 0];
    const float sy = posb[sp*3 + 1];
    const float sz = posb[sp*3 + 2];

    // ---- Phase 1: stream distances (reference rounding), per-lane sorted top-4 ----
    // Key: (distbits << 13) | idx — order == (dist, idx) lex; all keys distinct.
    u64 s0=SENT,s1=SENT,s2=SENT,s3=SENT;
#pragma unroll 4
    for (int c = 0; c < PPT; ++c) {
        const int i = c * NTH + t;                 // coalesced across lanes
        const float dx = __fsub_rn(sx, posb[i*3 + 0]);
        const float dy = __fsub_rn(sy, posb[i*3 + 1]);
        const float dz = __fsub_rn(sz, posb[i*3 + 2]);
        const float sq = __fadd_rn(__fadd_rn(__fmul_rn(dx,dx), __fmul_rn(dy,dy)),
                                   __fmul_rn(dz,dz));
        const u64 kv = ((u64)__float_as_uint(__fsqrt_rn(sq)) << 13) | (u32)i;
        INS(kv);
    }

    // ---- Phase 2: wave-level threshold selection (ballot binary search) ----
    {
        u64 L = 0;
        for (int bit = 43; bit >= 13; --bit) {     // distbit part first
            const u64 cand = L | (1ull << bit);
            const int cnt = __popcll(__ballot(s0 < cand)) + __popcll(__ballot(s1 < cand))
                          + __popcll(__ballot(s2 < cand)) + __popcll(__ballot(s3 < cand));
            if (cnt < 32) L = cand;
        }
        u64 TH = L + (1ull << 13);                 // candidate cut: distbits <= D
        {
            const int cnt = __popcll(__ballot(s0 < TH)) + __popcll(__ballot(s1 < TH))
                          + __popcll(__ballot(s2 < TH)) + __popcll(__ballot(s3 < TH));
            if (cnt != 32) {                       // distbit tie at cut: resolve by idx
                for (int bit = 12; bit >= 0; --bit) {
                    const u64 cand = L | (1ull << bit);
                    const int c2 = __popcll(__ballot(s0 < cand)) + __popcll(__ballot(s1 < cand))
                                 + __popcll(__ballot(s2 < cand)) + __popcll(__ballot(s3 < cand));
                    if (c2 < 32) L = cand;
                }
                TH = L + 1;                        // select = key <= L
            }
        }
        const bool b0 = s0 < TH, b1 = s1 < TH, b2 = s2 < TH, b3 = s3 < TH;
        const int csel = (int)b0 + (int)b1 + (int)b2 + (int)b3;

        if (__ballot(csel == 4) != 0ull) {
            // Saturated lane (possible hidden 5th key < TH): proven serial fallback.
            int nv = 4;
#pragma unroll 1
            for (int it = 0; it < KK; ++it) {
                u64 m = s0;
#pragma unroll
                for (int off = 32; off > 0; off >>= 1) {
                    const u64 o = __shfl_xor(m, off, 64);
                    m = o < m ? o : m;
                }
                if (lane == 0) wl[wv*KK + it] = m;
                if (s0 == m) {
                    s0=s1; s1=s2; s2=s3; s3=SENT;
                    if (--nv == 0) {                // refill from stream, keys > m
                        const u64 last = m;
                        s0=s1=s2=s3=SENT;
#pragma unroll 4
                        for (int c = 0; c < PPT; ++c) {
                            const int i = c * NTH + t;
                            const float dx = __fsub_rn(sx, posb[i*3 + 0]);
                            const float dy = __fsub_rn(sy, posb[i*3 + 1]);
                            const float dz = __fsub_rn(sz, posb[i*3 + 2]);
                            const float sq = __fadd_rn(__fadd_rn(__fmul_rn(dx,dx), __fmul_rn(dy,dy)),
                                                       __fmul_rn(dz,dz));
                            u64 kv = ((u64)__float_as_uint(__fsqrt_rn(sq)) << 13) | (u32)i;
                            kv = kv > last ? kv : SENT;
                            INS(kv);
                        }
                        nv = (int)(s0!=SENT)+(int)(s1!=SENT)+(int)(s2!=SENT)+(int)(s3!=SENT);
                    }
                }
            }
        } else {
            // Exact-32 fast path: compact selected keys (unsorted; order irrelevant).
            const u64 m0 = __ballot(b0), m1 = __ballot(b1),
                      m2 = __ballot(b2), m3 = __ballot(b3);
            const int pos2 = mbcnt64(m0) + mbcnt64(m1) + mbcnt64(m2) + mbcnt64(m3);
            u64* wwl = &wl[wv * KK];
            if (b0) wwl[pos2]     = s0;
            if (b1) wwl[pos2 + 1] = s1;
            if (b2) wwl[pos2 + 2] = s2;
            if (b3) wwl[pos2 + 3] = s3;
        }
    }
    __syncthreads();

    // ---- Phase 2b: block stage — top-32 of the 128 wave-selected keys ----
    if (t < 64) {
        const u64 k0 = wl[lane], k1 = wl[64 + lane];   // 2 keys/lane, fully known
        u64 L = 0;
        for (int bit = 43; bit >= 13; --bit) {
            const u64 cand = L | (1ull << bit);
            const int cnt = __popcll(__ballot(k0 < cand)) + __popcll(__ballot(k1 < cand));
            if (cnt < 32) L = cand;
        }
        u64 TH = L + (1ull << 13);
        {
            const int cnt = __popcll(__ballot(k0 < TH)) + __popcll(__ballot(k1 < TH));
            if (cnt != 32) {
                for (int bit = 12; bit >= 0; --bit) {
                    const u64 cand = L | (1ull << bit);
                    const int c2 = __popcll(__ballot(k0 < cand)) + __popcll(__ballot(k1 < cand));
                    if (c2 < 32) L = cand;
                }
                TH = L + 1;
            }
        }
        const bool c0 = k0 < TH, c1 = k1 < TH;
        const int p = mbcnt64(__ballot(c0)) + mbcnt64(__ballot(c1));
        if (c0) nbr[p]            = (int)(k0 & 8191u);
        if (c1) nbr[p + (int)c0]  = (int)(k1 & 8191u);
    }
    __syncthreads();

    // ---- Phase 3: gather neighbor coords (float4-strided for b128 reads) ----
    if (t < KK * 3) {
        const int k = t / 3, d = t - 3 * k;
        nbc[k * 4 + d] = posb[(size_t)nbr[k] * 3 + d];
    }
    __syncthreads();

    // ---- Phase 4: h0 = coords @ w_in + b_in + sincos PE -> bf16 (thread = channel) ----
    {
        const int  c     = t;
        const int  dimi  = c / 84;                  // 84 = 2*42 channels per dim
        const int  cc    = c - dimi * 84;
        const bool hasPe = c < 252;
        const bool isCos = cc >= 42;
        const int  f     = isCos ? cc - 42 : cc;
        const float fcoef = (float)(-9.210340371976184 / 41.0);
        const float freqv = expf((float)f * fcoef);
        const int  di    = hasPe ? dimi : 0;

        const float wi0 = w_in[0*HID + c];
        const float wi1 = w_in[1*HID + c];
        const float wi2 = w_in[2*HID + c];
        const float bi  = b_in[c];

#pragma unroll 4
        for (int k = 0; k < KK; ++k) {
            const float4 xv4 = *(const float4*)&nbc[k * 4];   // one b128 read
            const float x0 = xv4.x, x1 = xv4.y, x2 = xv4.z;
            float v = fmaf(x2, wi2, fmaf(x1, wi1, fmaf(x0, wi0, bi)));
            if (hasPe) {
                const float xv  = (di == 0) ? x0 : ((di == 1) ? x1 : x2);
                const float ang = xv * freqv;
                v += isCos ? __cosf(ang) : __sinf(ang);   // native (args |x|<~6)
            }
            h0b[k][c] = bf_bits(v);
        }
    }
    __syncthreads();

    // ---- MLP via bf16 MFMA, split weights (hi+lo) ----
    // A frag (16x16x32): row = lane&15, k = ks*32 + (lane>>4)*8 + j  (matches prep).
    // C/D: col = lane&15, row = (lane>>4)*4 + reg   [HW-verified m89]
    const int lr = lane & 15;
    const int lg = lane >> 4;
    const int nbase = wv * 64;

    const short* arow0 = &h0b[lr][lg * 8];
    const short* arow1 = &h0b[16 + lr][lg * 8];
    // per-wave weight base: slot = mat*131072 + ks*16384 + (wv*4+nt)*1024 + hl*512 + lane*8
    const __hip_bfloat16* wb1 = wf + (size_t)wv * 4096 + lane * 8;
    const __hip_bfloat16* wb2 = wb1 + 2 * WFE;

    f32x4 acc[2][4];

    // ---- layer 1: h1 = h0 @ w1 + b1 ----
    {
#pragma unroll
        for (int nt = 0; nt < 4; ++nt) {
            const float bias = b1[nbase + nt*16 + lr];
            const f32x4 bv = {bias, bias, bias, bias};
            acc[0][nt] = bv; acc[1][nt] = bv;
        }
#pragma unroll 1
        for (int ks = 0; ks < 8; ++ks) {
            const bf16x8 af0 = *(const bf16x8*)(arow0 + ks * 32);
            const bf16x8 af1 = *(const bf16x8*)(arow1 + ks * 32);
            const __hip_bfloat16* p = wb1 + ks * 16384;
#pragma unroll
            for (int nt = 0; nt < 4; ++nt) {
                const bf16x8 bh = *(const bf16x8*)(p + nt * 1024);
                acc[0][nt] = __builtin_amdgcn_mfma_f32_16x16x32_bf16(af0, bh, acc[0][nt], 0,0,0);
                acc[1][nt] = __builtin_amdgcn_mfma_f32_16x16x32_bf16(af1, bh, acc[1][nt], 0,0,0);
                const bf16x8 bl = *(const bf16x8*)(p + nt * 1024 + 512);
                acc[0][nt] = __builtin_amdgcn_mfma_f32_16x16x32_bf16(af0, bl, acc[0][nt], 0,0,0);
                acc[1][nt] = __builtin_amdgcn_mfma_f32_16x16x32_bf16(af1, bl, acc[1][nt], 0,0,0);
            }
        }
    }
    __syncthreads();                                 // all layer-1 h0 reads done

    // gelu (tanh approx) -> h0b (bf16; same rounding as before)
    {
        const float kA = 0.7978845608028654f;        // sqrt(2/pi)
#pragma unroll
        for (int mt = 0; mt < 2; ++mt)
#pragma unroll
        for (int nt = 0; nt < 4; ++nt)
#pragma unroll
        for (int r = 0; r < 4; ++r) {
            const float x  = acc[mt][nt][r];
            const float x3 = x * x * x;
            const float tv = tanh_fast(kA * fmaf(0.044715f, x3, x));
            h0b[mt*16 + lg*4 + r][nbase + nt*16 + lr] = bf_bits(0.5f * x * (1.0f + tv));
        }
    }
    __syncthreads();

    // ---- layer 2: g @ w2 (bias+mean folded into epilogue) ----
    {
        const f32x4 z = {0.f, 0.f, 0.f, 0.f};
#pragma unroll
        for (int nt = 0; nt < 4; ++nt) { acc[0][nt] = z; acc[1][nt] = z; }
#pragma unroll 1
        for (int ks = 0; ks < 8; ++ks) {
            const bf16x8 af0 = *(const bf16x8*)(arow0 + ks * 32);
            const bf16x8 af1 = *(const bf16x8*)(arow1 + ks * 32);
            const __hip_bfloat16* p = wb2 + ks * 16384;
#pragma unroll
            for (int nt = 0; nt < 4; ++nt) {
                const bf16x8 bh = *(const bf16x8*)(p + nt * 1024);
                acc[0][nt] = __builtin_amdgcn_mfma_f32_16x16x32_bf16(af0, bh, acc[0][nt], 0,0,0);
                acc[1][nt] = __builtin_amdgcn_mfma_f32_16x16x32_bf16(af1, bh, acc[1][nt], 0,0,0);
                const bf16x8 bl = *(const bf16x8*)(p + nt * 1024 + 512);
                acc[0][nt] = __builtin_amdgcn_mfma_f32_16x16x32_bf16(af0, bl, acc[0][nt], 0,0,0);
                acc[1][nt] = __builtin_amdgcn_mfma_f32_16x16x32_bf16(af1, bl, acc[1][nt], 0,0,0);
            }
        }
    }

    // ---- epilogue: mean over 32 rows + b2; lanes<16 write the wave's 64 channels ----
#pragma unroll
    for (int nt = 0; nt < 4; ++nt) {
        float ssum = 0.0f;
#pragma unroll
        for (int mt = 0; mt < 2; ++mt)
#pragma unroll
            for (int r = 0; r < 4; ++r) ssum += acc[mt][nt][r];
        ssum += __shfl_xor(ssum, 16, 64);            // sum over lane-groups
        ssum += __shfl_xor(ssum, 32, 64);
        if (lane < 16) {
            const int ch = nbase + nt*16 + lane;
            out[(size_t)bs * HID + ch] = fmaf(ssum, 1.0f / KK, b2[ch]);
        }
    }
}

extern "C" void kernel_launch(void* const* d_in, const int* in_sizes, int n_in,
                              void* d_out, int out_size, void* d_ws, size_t ws_size,
                              hipStream_t stream) {
    const float* pos  = (const float*)d_in[0];
    const int*   sni  = (const int*)  d_in[1];
    const float* w_in = (const float*)d_in[2];
    const float* b_in = (const float*)d_in[3];
    const float* w1   = (const float*)d_in[4];
    const float* b1   = (const float*)d_in[5];
    const float* w2   = (const float*)d_in[6];
    const float* b2   = (const float*)d_in[7];
    float* out = (float*)d_out;
    __hip_bfloat16* wf = (__hip_bfloat16*)d_ws;      // 4*65536*2B = 512 KB
    (void)ws_size; (void)in_sizes; (void)n_in; (void)out_size;

    hipLaunchKernelGGL(prep_w, dim3(2 * WFE / 256), dim3(256), 0, stream, w1, w2, wf);
    hipLaunchKernelGGL(snp_kernel, dim3(BB * SS), dim3(NTH), 0, stream,
                       pos, sni, w_in, b_in, b1, b2, wf, out);
}